// Round 5
// baseline (192.938 us; speedup 1.0000x reference)
//
#include <hip/hip_runtime.h>
#include <stdint.h>

typedef __attribute__((ext_vector_type(8))) __bf16 bf16x8;
typedef __attribute__((ext_vector_type(4))) float f32x4;
typedef __attribute__((ext_vector_type(16))) float f32x16;

#define MFMA16(a, b, c) __builtin_amdgcn_mfma_f32_16x16x32_bf16((a), (b), (c), 0, 0, 0)
#define MFMA32(a, b, c) __builtin_amdgcn_mfma_f32_32x32x16_bf16((a), (b), (c), 0, 0, 0)

__device__ __forceinline__ uint16_t f2b(float f) {
    union { float f; uint32_t u; } v; v.f = f;
    uint32_t u = v.u;
    return (uint16_t)((u + 0x7FFFu + ((u >> 16) & 1u)) >> 16);
}

__device__ __forceinline__ bf16x8 ldb8(const uint16_t* p) {
    return *(const bf16x8*)p;
}

// exp2 as a compiler-visible intrinsic (NOT inline asm: the hazard recognizer
// must see the TRANS op to insert MFMA->VALU / TRANS->VALU wait states).
__device__ __forceinline__ float exp2_fast(float x) {
#if __has_builtin(__builtin_amdgcn_exp2f)
    return __builtin_amdgcn_exp2f(x);
#else
    return __expf(x * 0.6931471805599453f);
#endif
}

// ---------------------------------------------------------------------------
// Kernel 0: pack weights to bf16.  Wall[320][256] = [Wq;Wk;Wv], ball[320],
// Wobf[256][512].  Wq/bq pre-scaled by log2(e) so attention uses exp2.
// ---------------------------------------------------------------------------
__global__ void pack_kernel(const float* __restrict__ Wq, const float* __restrict__ Wk,
                            const float* __restrict__ Wv, const float* __restrict__ bq,
                            const float* __restrict__ bk, const float* __restrict__ bv,
                            const float* __restrict__ Wo,
                            uint16_t* __restrict__ Wall, uint16_t* __restrict__ Wobf,
                            float* __restrict__ ball) {
    const float LOG2E = 1.4426950408889634f;
    int i = blockIdx.x * blockDim.x + threadIdx.x;
    int stride = gridDim.x * blockDim.x;
    for (int idx = i; idx < 320 * 256; idx += stride) {
        int r = idx >> 8, c = idx & 255;
        float v = (r < 32) ? Wq[r * 256 + c] * LOG2E
                 : (r < 64) ? Wk[(r - 32) * 256 + c]
                            : Wv[(r - 64) * 256 + c];
        Wall[idx] = f2b(v);
    }
    for (int idx = i; idx < 256 * 512; idx += stride) Wobf[idx] = f2b(Wo[idx]);
    for (int idx = i; idx < 320; idx += stride)
        ball[idx] = (idx < 32) ? bq[idx] * LOG2E
                  : (idx < 64) ? bk[idx - 32] : bv[idx - 64];
}

// ---------------------------------------------------------------------------
// Kernel 1: QKV projection.
// grid 256 = b(4) x ntile(64).  Emits qt[b][n][32], kt[b][n][32] (transposed,
// k-contiguous) and v[b][c][n] (c-major), all bf16.
// ---------------------------------------------------------------------------
__global__ __launch_bounds__(256) void qkv_kernel(
    const float* __restrict__ x, const uint16_t* __restrict__ Wall,
    const float* __restrict__ ball, uint16_t* __restrict__ qtg,
    uint16_t* __restrict__ ktg, uint16_t* __restrict__ vg) {
    __shared__ uint16_t xt[64][264];   // [n_local][c], pad 264

    const int b = blockIdx.x >> 6;
    const int n0 = (blockIdx.x & 63) * 64;
    const int t = threadIdx.x;
    const float* xb = x + (size_t)b * 256 * 4096;

    {
        const int nPart = t & 15, cIdx = t >> 4;
#pragma unroll
        for (int rep = 0; rep < 16; rep++) {
            int c = rep * 16 + cIdx;
            float4 f = *(const float4*)(xb + (size_t)c * 4096 + n0 + nPart * 4);
            xt[nPart * 4 + 0][c] = f2b(f.x);
            xt[nPart * 4 + 1][c] = f2b(f.y);
            xt[nPart * 4 + 2][c] = f2b(f.z);
            xt[nPart * 4 + 3][c] = f2b(f.w);
        }
    }
    __syncthreads();

    const int w = t >> 6, lane = t & 63, l15 = lane & 15, g = lane >> 4;

    // --- qk: D[n(64), o(64)], wave w owns m-tile w ---
    f32x4 accqk[4] = {};
#pragma unroll
    for (int ks = 0; ks < 8; ks++) {
        bf16x8 af = ldb8(&xt[w * 16 + l15][ks * 32 + g * 8]);
#pragma unroll
        for (int ot = 0; ot < 4; ot++) {
            bf16x8 bfr = ldb8(Wall + (ot * 16 + l15) * 256 + ks * 32 + g * 8);
            accqk[ot] = MFMA16(af, bfr, accqk[ot]);
        }
    }
#pragma unroll
    for (int ot = 0; ot < 4; ot++) {
        int o = ot * 16 + l15;
        float bias = ball[o];
#pragma unroll
        for (int r = 0; r < 4; r++) {
            int n = n0 + w * 16 + g * 4 + r;
            float v = accqk[ot][r] + bias;
            if (ot < 2) qtg[((size_t)b * 4096 + n) * 32 + o] = f2b(v);
            else        ktg[((size_t)b * 4096 + n) * 32 + (o - 32)] = f2b(v);
        }
    }

    // --- v: D[o(256), n(64)], wave w owns o-tiles 4w..4w+3 ---
    f32x4 accv[4][4] = {};
#pragma unroll
    for (int ks = 0; ks < 8; ks++) {
        bf16x8 av[4], bv4[4];
#pragma unroll
        for (int mt = 0; mt < 4; mt++)
            av[mt] = ldb8(Wall + (64 + (w * 4 + mt) * 16 + l15) * 256 + ks * 32 + g * 8);
#pragma unroll
        for (int nt = 0; nt < 4; nt++)
            bv4[nt] = ldb8(&xt[nt * 16 + l15][ks * 32 + g * 8]);
#pragma unroll
        for (int mt = 0; mt < 4; mt++)
#pragma unroll
            for (int nt = 0; nt < 4; nt++)
                accv[mt][nt] = MFMA16(av[mt], bv4[nt], accv[mt][nt]);
    }
#pragma unroll
    for (int mt = 0; mt < 4; mt++) {
#pragma unroll
        for (int r = 0; r < 4; r++) {
            int o = (w * 4 + mt) * 16 + g * 4 + r;
            float bias = ball[64 + o];
#pragma unroll
            for (int nt = 0; nt < 4; nt++) {
                int n = n0 + nt * 16 + l15;
                vg[((size_t)b * 256 + o) * 4096 + n] = f2b(accv[mt][nt][r] + bias);
            }
        }
    }
}

// ---------------------------------------------------------------------------
// Kernel 2: flash attention v5 — barrier-free, LDS-free, 2 blocks/CU.
// grid 512 = b(4) x mtile(128) (32 m-rows each), XCD-swizzled; 4 waves.
// Each wave: the block's 32 m-rows x its own 64-channel slice.  S^T =
// MFMA32(K,Q): lane (l31,hi) owns row m=m0+l31, n-halves split by hi.
// exp2 intrinsic (Wq pre-scaled by log2e) + lane-local row-sum; P->bf16 via
// native __bf16 casts (v_cvt_pk_bf16_f32); one dword-pair shfl_xor(32)
// assembles the PV A-frag.  K/V frags double-buffered in regs from global.
// No __syncthreads in the main loop.
// ---------------------------------------------------------------------------
__global__ __launch_bounds__(256, 2) void attn_kernel(
    const uint16_t* __restrict__ qtg, const uint16_t* __restrict__ ktg,
    const uint16_t* __restrict__ vg, uint16_t* __restrict__ og) {
    __shared__ float ls[4][32];

    const int bid = blockIdx.x;
    const int swz = (bid & 7) * 64 + (bid >> 3);   // XCD-chunked (512%8==0)
    const int b = swz >> 7;
    const int m0 = (swz & 127) * 32;
    const int t = threadIdx.x, w = t >> 6, lane = t & 63;
    const int l31 = lane & 31, hi = lane >> 5;

    const uint16_t* qb = qtg + (size_t)b * 4096 * 32;
    const uint16_t* kb = ktg + (size_t)b * 4096 * 32;
    const uint16_t* vb = vg  + (size_t)b * 256 * 4096;

    bf16x8 qf[2];
#pragma unroll
    for (int ks = 0; ks < 2; ks++)
        qf[ks] = ldb8(qb + (size_t)(m0 + l31) * 32 + ks * 16 + hi * 8);

    const uint16_t* kbase = kb + l31 * 32 + hi * 8;
    const uint16_t* vbase = vb + (size_t)(w * 64 + l31) * 4096 + hi * 8;

    f32x16 acc[2] = {};        // [ct]: O[m0+rows][w*64+ct*32+l31]
    float lpart = 0.f;

    auto loadK = [&](int ch, bf16x8* kf) {
#pragma unroll
        for (int ks = 0; ks < 2; ks++)
            kf[ks] = ldb8(kbase + ch * 1024 + ks * 16);
    };
    auto loadV = [&](int ch, bf16x8 (*vf)[2]) {
#pragma unroll
        for (int ct = 0; ct < 2; ct++)
#pragma unroll
            for (int ks = 0; ks < 2; ks++)
                vf[ct][ks] = ldb8(vbase + (size_t)ct * 32 * 4096 + ch * 32 + ks * 16);
    };

    auto step = [&](const bf16x8* kf, const bf16x8 (*vf)[2]) {
        f32x16 z = {};
        f32x16 s = MFMA32(kf[0], qf[0], z);
        s = MFMA32(kf[1], qf[1], s);
        // lane (l31,hi) reg r: n = (r&3)+8*(r>>2)+4*hi, m = m0+l31
        float e[16];
#pragma unroll
        for (int r = 0; r < 16; r++) e[r] = exp2_fast(s[r]);
        float sum = 0.f;
#pragma unroll
        for (int r = 0; r < 16; r++) sum += e[r];
        lpart += sum;

        bf16x8 paf[2];
#pragma unroll
        for (int ks = 0; ks < 2; ks++) {
            union { bf16x8 v; __bf16 h[8]; uint32_t d[4]; } u;
#pragma unroll
            for (int j = 0; j < 8; j++) u.h[j] = (__bf16)e[8 * ks + j];
            uint32_t g0 = hi ? u.d[0] : u.d[2];
            uint32_t g1 = hi ? u.d[1] : u.d[3];
            uint32_t r0 = (uint32_t)__shfl_xor((int)g0, 32);
            uint32_t r1 = (uint32_t)__shfl_xor((int)g1, 32);
            if (hi == 0) { u.d[2] = r0; u.d[3] = r1; }
            else         { u.d[0] = r0; u.d[1] = r1; }
            paf[ks] = u.v;
        }
#pragma unroll
        for (int ks = 0; ks < 2; ks++)
#pragma unroll
            for (int ct = 0; ct < 2; ct++)
                acc[ct] = MFMA32(paf[ks], vf[ct][ks], acc[ct]);
    };

    bf16x8 kfA[2], kfB[2], vfA[2][2], vfB[2][2];
    loadK(0, kfA); loadV(0, vfA);
    loadK(1, kfB); loadV(1, vfB);

    for (int ch = 0; ch < 128; ch += 2) {
        step(kfA, vfA);
        if (ch + 2 < 128) { loadK(ch + 2, kfA); loadV(ch + 2, vfA); }
        step(kfB, vfB);
        if (ch + 3 < 128) { loadK(ch + 3, kfB); loadV(ch + 3, vfB); }
    }

    // row-sum: lane (l31,hi) holds half of row m0+l31; combine across hi
    {
        float rs = lpart + __shfl_xor(lpart, 32);
        if (hi == 0) ls[w][l31] = 1.0f / rs;
    }
    __syncthreads();

#pragma unroll
    for (int r = 0; r < 16; r++) {
        const int rowm = (r & 3) + 8 * (r >> 2) + 4 * hi;
        const float rinv = ls[w][rowm];
        const size_t rowo = ((size_t)b * 4096 + m0 + rowm) * 256 + w * 64 + l31;
#pragma unroll
        for (int ct = 0; ct < 2; ct++)
            og[rowo + ct * 32] = f2b(acc[ct][r] * rinv);
    }
}

// ---------------------------------------------------------------------------
// Kernel 3: y = Wo[:, :256] @ out + Wo[:, 256:] @ x + bo.
// ---------------------------------------------------------------------------
__global__ __launch_bounds__(256) void out_kernel(
    const float* __restrict__ x, const uint16_t* __restrict__ og,
    const uint16_t* __restrict__ Wobf, const float* __restrict__ bo,
    float* __restrict__ y) {
    __shared__ uint16_t xt[64][264];

    const int b = blockIdx.x >> 6;
    const int m0 = (blockIdx.x & 63) * 64;
    const int t = threadIdx.x;
    const float* xb = x + (size_t)b * 256 * 4096;

    {
        const int nPart = t & 15, cIdx = t >> 4;
#pragma unroll
        for (int rep = 0; rep < 16; rep++) {
            int c = rep * 16 + cIdx;
            float4 f = *(const float4*)(xb + (size_t)c * 4096 + m0 + nPart * 4);
            xt[nPart * 4 + 0][c] = f2b(f.x);
            xt[nPart * 4 + 1][c] = f2b(f.y);
            xt[nPart * 4 + 2][c] = f2b(f.z);
            xt[nPart * 4 + 3][c] = f2b(f.w);
        }
    }
    __syncthreads();

    const int w = t >> 6, lane = t & 63, l15 = lane & 15, g = lane >> 4;
    const uint16_t* ob = og + ((size_t)b * 4096 + m0) * 256;

    f32x4 acc[4][4] = {};
#pragma unroll
    for (int ks = 0; ks < 8; ks++) {
        bf16x8 af[4], bfr[4];
#pragma unroll
        for (int mt = 0; mt < 4; mt++)
            af[mt] = ldb8(Wobf + ((w * 4 + mt) * 16 + l15) * 512 + ks * 32 + g * 8);
#pragma unroll
        for (int nt = 0; nt < 4; nt++)
            bfr[nt] = ldb8(ob + (size_t)(nt * 16 + l15) * 256 + ks * 32 + g * 8);
#pragma unroll
        for (int mt = 0; mt < 4; mt++)
#pragma unroll
            for (int nt = 0; nt < 4; nt++)
                acc[mt][nt] = MFMA16(af[mt], bfr[nt], acc[mt][nt]);
    }
#pragma unroll
    for (int ks = 0; ks < 8; ks++) {
        bf16x8 af[4], bfr[4];
#pragma unroll
        for (int mt = 0; mt < 4; mt++)
            af[mt] = ldb8(Wobf + ((w * 4 + mt) * 16 + l15) * 512 + 256 + ks * 32 + g * 8);
#pragma unroll
        for (int nt = 0; nt < 4; nt++)
            bfr[nt] = ldb8(&xt[nt * 16 + l15][ks * 32 + g * 8]);
#pragma unroll
        for (int mt = 0; mt < 4; mt++)
#pragma unroll
            for (int nt = 0; nt < 4; nt++)
                acc[mt][nt] = MFMA16(af[mt], bfr[nt], acc[mt][nt]);
    }

#pragma unroll
    for (int mt = 0; mt < 4; mt++)
#pragma unroll
        for (int r = 0; r < 4; r++) {
            int o = (w * 4 + mt) * 16 + g * 4 + r;
            float bias = bo[o];
#pragma unroll
            for (int nt = 0; nt < 4; nt++) {
                int m = m0 + nt * 16 + l15;
                y[((size_t)b * 256 + o) * 4096 + m] = acc[mt][nt][r] + bias;
            }
        }
}

// ---------------------------------------------------------------------------
extern "C" void kernel_launch(void* const* d_in, const int* in_sizes, int n_in,
                              void* d_out, int out_size, void* d_ws, size_t ws_size,
                              hipStream_t stream) {
    const float* x  = (const float*)d_in[0];
    const float* Wq = (const float*)d_in[1];
    const float* bq = (const float*)d_in[2];
    const float* Wk = (const float*)d_in[3];
    const float* bk = (const float*)d_in[4];
    const float* Wv = (const float*)d_in[5];
    const float* bv = (const float*)d_in[6];
    const float* Wo = (const float*)d_in[7];
    const float* bo = (const float*)d_in[8];
    float* y = (float*)d_out;

    char* ws = (char*)d_ws;
    uint16_t* Wall = (uint16_t*)(ws + 0);          // 163840 B
    uint16_t* Wobf = (uint16_t*)(ws + 163840);     // 262144 B
    float*    ball = (float*)(ws + 425984);        // 1280 B
    uint16_t* qtg  = (uint16_t*)(ws + 427520);     // 1 MiB
    uint16_t* ktg  = (uint16_t*)(ws + 1476096);    // 1 MiB
    uint16_t* vgw  = (uint16_t*)(ws + 2524672);    // 8 MiB
    uint16_t* ogw  = (uint16_t*)(ws + 10913280);   // 8 MiB

    pack_kernel<<<256, 256, 0, stream>>>(Wq, Wk, Wv, bq, bk, bv, Wo, Wall, Wobf, ball);
    qkv_kernel<<<256, 256, 0, stream>>>(x, Wall, ball, qtg, ktg, vgw);
    attn_kernel<<<512, 256, 0, stream>>>(qtg, ktg, vgw, ogw);
    out_kernel<<<256, 256, 0, stream>>>(x, ogw, Wobf, bo, y);
}

// Round 6
// 192.537 us; speedup vs baseline: 1.0021x; 1.0021x over previous
//
#include <hip/hip_runtime.h>
#include <stdint.h>

typedef __attribute__((ext_vector_type(8))) __bf16 bf16x8;
typedef __attribute__((ext_vector_type(4))) float f32x4;
typedef __attribute__((ext_vector_type(16))) float f32x16;

#define MFMA16(a, b, c) __builtin_amdgcn_mfma_f32_16x16x32_bf16((a), (b), (c), 0, 0, 0)
#define MFMA32(a, b, c) __builtin_amdgcn_mfma_f32_32x32x16_bf16((a), (b), (c), 0, 0, 0)

__device__ __forceinline__ uint16_t f2b(float f) {
    union { float f; uint32_t u; } v; v.f = f;
    uint32_t u = v.u;
    return (uint16_t)((u + 0x7FFFu + ((u >> 16) & 1u)) >> 16);
}

__device__ __forceinline__ bf16x8 ldb8(const uint16_t* p) {
    return *(const bf16x8*)p;
}

// exp2 as a compiler-visible intrinsic (NOT inline asm: the hazard recognizer
// must see the TRANS op to insert MFMA->VALU / TRANS->VALU wait states).
__device__ __forceinline__ float exp2_fast(float x) {
#if __has_builtin(__builtin_amdgcn_exp2f)
    return __builtin_amdgcn_exp2f(x);
#else
    return __expf(x * 0.6931471805599453f);
#endif
}

// ---------------------------------------------------------------------------
// Kernel 0: pack weights to bf16.  Wall[320][256] = [Wq;Wk;Wv], ball[320],
// Wobf[256][512].  Wq/bq pre-scaled by log2(e) so attention uses exp2.
// ---------------------------------------------------------------------------
__global__ void pack_kernel(const float* __restrict__ Wq, const float* __restrict__ Wk,
                            const float* __restrict__ Wv, const float* __restrict__ bq,
                            const float* __restrict__ bk, const float* __restrict__ bv,
                            const float* __restrict__ Wo,
                            uint16_t* __restrict__ Wall, uint16_t* __restrict__ Wobf,
                            float* __restrict__ ball) {
    const float LOG2E = 1.4426950408889634f;
    int i = blockIdx.x * blockDim.x + threadIdx.x;
    int stride = gridDim.x * blockDim.x;
    for (int idx = i; idx < 320 * 256; idx += stride) {
        int r = idx >> 8, c = idx & 255;
        float v = (r < 32) ? Wq[r * 256 + c] * LOG2E
                 : (r < 64) ? Wk[(r - 32) * 256 + c]
                            : Wv[(r - 64) * 256 + c];
        Wall[idx] = f2b(v);
    }
    for (int idx = i; idx < 256 * 512; idx += stride) Wobf[idx] = f2b(Wo[idx]);
    for (int idx = i; idx < 320; idx += stride)
        ball[idx] = (idx < 32) ? bq[idx] * LOG2E
                  : (idx < 64) ? bk[idx - 32] : bv[idx - 64];
}

// ---------------------------------------------------------------------------
// Kernel 1: QKV projection.
// grid 256 = b(4) x ntile(64).  Emits qt[b][n][32], kt[b][n][32] (transposed,
// k-contiguous) and v[b][c][n] (c-major), all bf16.
// ---------------------------------------------------------------------------
__global__ __launch_bounds__(256) void qkv_kernel(
    const float* __restrict__ x, const uint16_t* __restrict__ Wall,
    const float* __restrict__ ball, uint16_t* __restrict__ qtg,
    uint16_t* __restrict__ ktg, uint16_t* __restrict__ vg) {
    __shared__ uint16_t xt[64][264];   // [n_local][c], pad 264

    const int b = blockIdx.x >> 6;
    const int n0 = (blockIdx.x & 63) * 64;
    const int t = threadIdx.x;
    const float* xb = x + (size_t)b * 256 * 4096;

    {
        const int nPart = t & 15, cIdx = t >> 4;
#pragma unroll
        for (int rep = 0; rep < 16; rep++) {
            int c = rep * 16 + cIdx;
            float4 f = *(const float4*)(xb + (size_t)c * 4096 + n0 + nPart * 4);
            xt[nPart * 4 + 0][c] = f2b(f.x);
            xt[nPart * 4 + 1][c] = f2b(f.y);
            xt[nPart * 4 + 2][c] = f2b(f.z);
            xt[nPart * 4 + 3][c] = f2b(f.w);
        }
    }
    __syncthreads();

    const int w = t >> 6, lane = t & 63, l15 = lane & 15, g = lane >> 4;

    // --- qk: D[n(64), o(64)], wave w owns m-tile w ---
    f32x4 accqk[4] = {};
#pragma unroll
    for (int ks = 0; ks < 8; ks++) {
        bf16x8 af = ldb8(&xt[w * 16 + l15][ks * 32 + g * 8]);
#pragma unroll
        for (int ot = 0; ot < 4; ot++) {
            bf16x8 bfr = ldb8(Wall + (ot * 16 + l15) * 256 + ks * 32 + g * 8);
            accqk[ot] = MFMA16(af, bfr, accqk[ot]);
        }
    }
#pragma unroll
    for (int ot = 0; ot < 4; ot++) {
        int o = ot * 16 + l15;
        float bias = ball[o];
#pragma unroll
        for (int r = 0; r < 4; r++) {
            int n = n0 + w * 16 + g * 4 + r;
            float v = accqk[ot][r] + bias;
            if (ot < 2) qtg[((size_t)b * 4096 + n) * 32 + o] = f2b(v);
            else        ktg[((size_t)b * 4096 + n) * 32 + (o - 32)] = f2b(v);
        }
    }

    // --- v: D[o(256), n(64)], wave w owns o-tiles 4w..4w+3 ---
    f32x4 accv[4][4] = {};
#pragma unroll
    for (int ks = 0; ks < 8; ks++) {
        bf16x8 av[4], bv4[4];
#pragma unroll
        for (int mt = 0; mt < 4; mt++)
            av[mt] = ldb8(Wall + (64 + (w * 4 + mt) * 16 + l15) * 256 + ks * 32 + g * 8);
#pragma unroll
        for (int nt = 0; nt < 4; nt++)
            bv4[nt] = ldb8(&xt[nt * 16 + l15][ks * 32 + g * 8]);
#pragma unroll
        for (int mt = 0; mt < 4; mt++)
#pragma unroll
            for (int nt = 0; nt < 4; nt++)
                accv[mt][nt] = MFMA16(av[mt], bv4[nt], accv[mt][nt]);
    }
#pragma unroll
    for (int mt = 0; mt < 4; mt++) {
#pragma unroll
        for (int r = 0; r < 4; r++) {
            int o = (w * 4 + mt) * 16 + g * 4 + r;
            float bias = ball[64 + o];
#pragma unroll
            for (int nt = 0; nt < 4; nt++) {
                int n = n0 + nt * 16 + l15;
                vg[((size_t)b * 256 + o) * 4096 + n] = f2b(accv[mt][nt][r] + bias);
            }
        }
    }
}

// ---------------------------------------------------------------------------
// Kernel 2: flash attention v6 — barrier-free, LDS-free, 2 blocks/CU,
// 4-deep register ring prefetch (distance 3-4 steps covers L2 latency).
// grid 512 = b(4) x mtile(128) (32 m-rows each), XCD-swizzled; 4 waves.
// Each wave: the block's 32 m-rows x its own 64-channel slice.  S^T =
// MFMA32(K,Q): lane (l31,hi) owns row m=m0+l31.  exp2 intrinsic (Wq
// pre-scaled by log2e) + lane-local row-sum; P->bf16 native casts; one
// dword-pair shfl_xor(32) assembles the PV A-frag.  No __syncthreads in
// the main loop.
// ---------------------------------------------------------------------------
__global__ __launch_bounds__(256, 2) void attn_kernel(
    const uint16_t* __restrict__ qtg, const uint16_t* __restrict__ ktg,
    const uint16_t* __restrict__ vg, uint16_t* __restrict__ og) {
    __shared__ float ls[4][32];

    const int bid = blockIdx.x;
    const int swz = (bid & 7) * 64 + (bid >> 3);   // XCD-chunked (512%8==0)
    const int b = swz >> 7;
    const int m0 = (swz & 127) * 32;
    const int t = threadIdx.x, w = t >> 6, lane = t & 63;
    const int l31 = lane & 31, hi = lane >> 5;

    const uint16_t* qb = qtg + (size_t)b * 4096 * 32;
    const uint16_t* kb = ktg + (size_t)b * 4096 * 32;
    const uint16_t* vb = vg  + (size_t)b * 256 * 4096;

    bf16x8 qf[2];
#pragma unroll
    for (int ks = 0; ks < 2; ks++)
        qf[ks] = ldb8(qb + (size_t)(m0 + l31) * 32 + ks * 16 + hi * 8);

    const uint16_t* kbase = kb + l31 * 32 + hi * 8;
    const uint16_t* vbase = vb + (size_t)(w * 64 + l31) * 4096 + hi * 8;

    f32x16 acc[2] = {};        // [ct]: O[m0+rows][w*64+ct*32+l31]
    float lpart = 0.f;

    auto loadK = [&](int ch, bf16x8* kf) {
#pragma unroll
        for (int ks = 0; ks < 2; ks++)
            kf[ks] = ldb8(kbase + ch * 1024 + ks * 16);
    };
    auto loadV = [&](int ch, bf16x8 (*vf)[2]) {
#pragma unroll
        for (int ct = 0; ct < 2; ct++)
#pragma unroll
            for (int ks = 0; ks < 2; ks++)
                vf[ct][ks] = ldb8(vbase + (size_t)ct * 32 * 4096 + ch * 32 + ks * 16);
    };

    auto step = [&](const bf16x8* kf, const bf16x8 (*vf)[2]) {
        f32x16 z = {};
        f32x16 s = MFMA32(kf[0], qf[0], z);
        s = MFMA32(kf[1], qf[1], s);
        // lane (l31,hi) reg r: n = (r&3)+8*(r>>2)+4*hi, m = m0+l31
        float e[16];
#pragma unroll
        for (int r = 0; r < 16; r++) e[r] = exp2_fast(s[r]);
        float sum = 0.f;
#pragma unroll
        for (int r = 0; r < 16; r++) sum += e[r];
        lpart += sum;

        bf16x8 paf[2];
#pragma unroll
        for (int ks = 0; ks < 2; ks++) {
            union { bf16x8 v; __bf16 h[8]; uint32_t d[4]; } u;
#pragma unroll
            for (int j = 0; j < 8; j++) u.h[j] = (__bf16)e[8 * ks + j];
            uint32_t g0 = hi ? u.d[0] : u.d[2];
            uint32_t g1 = hi ? u.d[1] : u.d[3];
            uint32_t r0 = (uint32_t)__shfl_xor((int)g0, 32);
            uint32_t r1 = (uint32_t)__shfl_xor((int)g1, 32);
            if (hi == 0) { u.d[2] = r0; u.d[3] = r1; }
            else         { u.d[0] = r0; u.d[1] = r1; }
            paf[ks] = u.v;
        }
#pragma unroll
        for (int ks = 0; ks < 2; ks++)
#pragma unroll
            for (int ct = 0; ct < 2; ct++)
                acc[ct] = MFMA32(paf[ks], vf[ct][ks], acc[ct]);
    };

    // 4-deep static ring buffer (all indices compile-time; rule #20)
    bf16x8 kf0[2], kf1[2], kf2[2], kf3[2];
    bf16x8 vf0[2][2], vf1[2][2], vf2[2][2], vf3[2][2];

    loadK(0, kf0); loadV(0, vf0);
    loadK(1, kf1); loadV(1, vf1);
    loadK(2, kf2); loadV(2, vf2);
    loadK(3, kf3); loadV(3, vf3);

    for (int ch = 0; ch < 124; ch += 4) {
        step(kf0, vf0); loadK(ch + 4, kf0); loadV(ch + 4, vf0);
        step(kf1, vf1); loadK(ch + 5, kf1); loadV(ch + 5, vf1);
        step(kf2, vf2); loadK(ch + 6, kf2); loadV(ch + 6, vf2);
        step(kf3, vf3); loadK(ch + 7, kf3); loadV(ch + 7, vf3);
    }
    step(kf0, vf0);
    step(kf1, vf1);
    step(kf2, vf2);
    step(kf3, vf3);

    // row-sum: lane (l31,hi) holds half of row m0+l31; combine across hi
    {
        float rs = lpart + __shfl_xor(lpart, 32);
        if (hi == 0) ls[w][l31] = 1.0f / rs;
    }
    __syncthreads();

#pragma unroll
    for (int r = 0; r < 16; r++) {
        const int rowm = (r & 3) + 8 * (r >> 2) + 4 * hi;
        const float rinv = ls[w][rowm];
        const size_t rowo = ((size_t)b * 4096 + m0 + rowm) * 256 + w * 64 + l31;
#pragma unroll
        for (int ct = 0; ct < 2; ct++)
            og[rowo + ct * 32] = f2b(acc[ct][r] * rinv);
    }
}

// ---------------------------------------------------------------------------
// Kernel 3: y = Wo[:, :256] @ out + Wo[:, 256:] @ x + bo.
// ---------------------------------------------------------------------------
__global__ __launch_bounds__(256) void out_kernel(
    const float* __restrict__ x, const uint16_t* __restrict__ og,
    const uint16_t* __restrict__ Wobf, const float* __restrict__ bo,
    float* __restrict__ y) {
    __shared__ uint16_t xt[64][264];

    const int b = blockIdx.x >> 6;
    const int m0 = (blockIdx.x & 63) * 64;
    const int t = threadIdx.x;
    const float* xb = x + (size_t)b * 256 * 4096;

    {
        const int nPart = t & 15, cIdx = t >> 4;
#pragma unroll
        for (int rep = 0; rep < 16; rep++) {
            int c = rep * 16 + cIdx;
            float4 f = *(const float4*)(xb + (size_t)c * 4096 + m0 + nPart * 4);
            xt[nPart * 4 + 0][c] = f2b(f.x);
            xt[nPart * 4 + 1][c] = f2b(f.y);
            xt[nPart * 4 + 2][c] = f2b(f.z);
            xt[nPart * 4 + 3][c] = f2b(f.w);
        }
    }
    __syncthreads();

    const int w = t >> 6, lane = t & 63, l15 = lane & 15, g = lane >> 4;
    const uint16_t* ob = og + ((size_t)b * 4096 + m0) * 256;

    f32x4 acc[4][4] = {};
#pragma unroll
    for (int ks = 0; ks < 8; ks++) {
        bf16x8 af[4], bfr[4];
#pragma unroll
        for (int mt = 0; mt < 4; mt++)
            af[mt] = ldb8(Wobf + ((w * 4 + mt) * 16 + l15) * 512 + ks * 32 + g * 8);
#pragma unroll
        for (int nt = 0; nt < 4; nt++)
            bfr[nt] = ldb8(ob + (size_t)(nt * 16 + l15) * 256 + ks * 32 + g * 8);
#pragma unroll
        for (int mt = 0; mt < 4; mt++)
#pragma unroll
            for (int nt = 0; nt < 4; nt++)
                acc[mt][nt] = MFMA16(af[mt], bfr[nt], acc[mt][nt]);
    }
#pragma unroll
    for (int ks = 0; ks < 8; ks++) {
        bf16x8 af[4], bfr[4];
#pragma unroll
        for (int mt = 0; mt < 4; mt++)
            af[mt] = ldb8(Wobf + ((w * 4 + mt) * 16 + l15) * 512 + 256 + ks * 32 + g * 8);
#pragma unroll
        for (int nt = 0; nt < 4; nt++)
            bfr[nt] = ldb8(&xt[nt * 16 + l15][ks * 32 + g * 8]);
#pragma unroll
        for (int mt = 0; mt < 4; mt++)
#pragma unroll
            for (int nt = 0; nt < 4; nt++)
                acc[mt][nt] = MFMA16(af[mt], bfr[nt], acc[mt][nt]);
    }

#pragma unroll
    for (int mt = 0; mt < 4; mt++)
#pragma unroll
        for (int r = 0; r < 4; r++) {
            int o = (w * 4 + mt) * 16 + g * 4 + r;
            float bias = bo[o];
#pragma unroll
            for (int nt = 0; nt < 4; nt++) {
                int m = m0 + nt * 16 + l15;
                y[((size_t)b * 256 + o) * 4096 + m] = acc[mt][nt][r] + bias;
            }
        }
}

// ---------------------------------------------------------------------------
extern "C" void kernel_launch(void* const* d_in, const int* in_sizes, int n_in,
                              void* d_out, int out_size, void* d_ws, size_t ws_size,
                              hipStream_t stream) {
    const float* x  = (const float*)d_in[0];
    const float* Wq = (const float*)d_in[1];
    const float* bq = (const float*)d_in[2];
    const float* Wk = (const float*)d_in[3];
    const float* bk = (const float*)d_in[4];
    const float* Wv = (const float*)d_in[5];
    const float* bv = (const float*)d_in[6];
    const float* Wo = (const float*)d_in[7];
    const float* bo = (const float*)d_in[8];
    float* y = (float*)d_out;

    char* ws = (char*)d_ws;
    uint16_t* Wall = (uint16_t*)(ws + 0);          // 163840 B
    uint16_t* Wobf = (uint16_t*)(ws + 163840);     // 262144 B
    float*    ball = (float*)(ws + 425984);        // 1280 B
    uint16_t* qtg  = (uint16_t*)(ws + 427520);     // 1 MiB
    uint16_t* ktg  = (uint16_t*)(ws + 1476096);    // 1 MiB
    uint16_t* vgw  = (uint16_t*)(ws + 2524672);    // 8 MiB
    uint16_t* ogw  = (uint16_t*)(ws + 10913280);   // 8 MiB

    pack_kernel<<<256, 256, 0, stream>>>(Wq, Wk, Wv, bq, bk, bv, Wo, Wall, Wobf, ball);
    qkv_kernel<<<256, 256, 0, stream>>>(x, Wall, ball, qtg, ktg, vgw);
    attn_kernel<<<512, 256, 0, stream>>>(qtg, ktg, vgw, ogw);
    out_kernel<<<256, 256, 0, stream>>>(x, ogw, Wobf, bo, y);
}

// Round 8
// 127.736 us; speedup vs baseline: 1.5105x; 1.5073x over previous
//
#include <hip/hip_runtime.h>
#include <stdint.h>

typedef __attribute__((ext_vector_type(8))) __bf16 bf16x8;
typedef __attribute__((ext_vector_type(4))) float f32x4;
typedef __attribute__((ext_vector_type(16))) float f32x16;

#define MFMA16(a, b, c) __builtin_amdgcn_mfma_f32_16x16x32_bf16((a), (b), (c), 0, 0, 0)
#define MFMA32(a, b, c) __builtin_amdgcn_mfma_f32_32x32x16_bf16((a), (b), (c), 0, 0, 0)

__device__ __forceinline__ uint16_t f2b(float f) {
    union { float f; uint32_t u; } v; v.f = f;
    uint32_t u = v.u;
    return (uint16_t)((u + 0x7FFFu + ((u >> 16) & 1u)) >> 16);
}

__device__ __forceinline__ bf16x8 ldb8(const uint16_t* p) {
    return *(const bf16x8*)p;
}

// exp2 as a compiler-visible intrinsic (hazard recognizer must see TRANS op).
__device__ __forceinline__ float exp2_fast(float x) {
#if __has_builtin(__builtin_amdgcn_exp2f)
    return __builtin_amdgcn_exp2f(x);
#else
    return __expf(x * 0.6931471805599453f);
#endif
}

// ---------------------------------------------------------------------------
// Kernel 0: pack weights to bf16.  Wall[320][256] = [Wq;Wk;Wv], ball[320],
// Wobf[256][512].  Wq/bq pre-scaled by log2(e) so attention uses exp2.
// ---------------------------------------------------------------------------
__global__ void pack_kernel(const float* __restrict__ Wq, const float* __restrict__ Wk,
                            const float* __restrict__ Wv, const float* __restrict__ bq,
                            const float* __restrict__ bk, const float* __restrict__ bv,
                            const float* __restrict__ Wo,
                            uint16_t* __restrict__ Wall, uint16_t* __restrict__ Wobf,
                            float* __restrict__ ball) {
    const float LOG2E = 1.4426950408889634f;
    int i = blockIdx.x * blockDim.x + threadIdx.x;
    int stride = gridDim.x * blockDim.x;
    for (int idx = i; idx < 320 * 256; idx += stride) {
        int r = idx >> 8, c = idx & 255;
        float v = (r < 32) ? Wq[r * 256 + c] * LOG2E
                 : (r < 64) ? Wk[(r - 32) * 256 + c]
                            : Wv[(r - 64) * 256 + c];
        Wall[idx] = f2b(v);
    }
    for (int idx = i; idx < 256 * 512; idx += stride) Wobf[idx] = f2b(Wo[idx]);
    for (int idx = i; idx < 320; idx += stride)
        ball[idx] = (idx < 32) ? bq[idx] * LOG2E
                  : (idx < 64) ? bk[idx - 32] : bv[idx - 64];
}

// ---------------------------------------------------------------------------
// Kernel 1: QKV projection.
// grid 256 = b(4) x ntile(64).  Emits:
//   qt[b][n][32]                       (k-contiguous rows, unchanged)
//   K'[b][ch(128)][ks(2)][n32][c16]    (attn K-frag load = contiguous 1KB)
//   V'[b][n/8(512)][c(256)][n%8(8)]    (attn V-frag load = coalesced)
// ---------------------------------------------------------------------------
__global__ __launch_bounds__(256) void qkv_kernel(
    const float* __restrict__ x, const uint16_t* __restrict__ Wall,
    const float* __restrict__ ball, uint16_t* __restrict__ qtg,
    uint16_t* __restrict__ ktg, uint16_t* __restrict__ vg) {
    __shared__ uint16_t xt[64][264];   // [n_local][c], pad 264

    const int b = blockIdx.x >> 6;
    const int n0 = (blockIdx.x & 63) * 64;
    const int t = threadIdx.x;
    const float* xb = x + (size_t)b * 256 * 4096;

    {
        const int nPart = t & 15, cIdx = t >> 4;
#pragma unroll
        for (int rep = 0; rep < 16; rep++) {
            int c = rep * 16 + cIdx;
            float4 f = *(const float4*)(xb + (size_t)c * 4096 + n0 + nPart * 4);
            xt[nPart * 4 + 0][c] = f2b(f.x);
            xt[nPart * 4 + 1][c] = f2b(f.y);
            xt[nPart * 4 + 2][c] = f2b(f.z);
            xt[nPart * 4 + 3][c] = f2b(f.w);
        }
    }
    __syncthreads();

    const int w = t >> 6, lane = t & 63, l15 = lane & 15, g = lane >> 4;

    // --- qk: D[n(64), o(64)], wave w owns m-tile w ---
    f32x4 accqk[4] = {};
#pragma unroll
    for (int ks = 0; ks < 8; ks++) {
        bf16x8 af = ldb8(&xt[w * 16 + l15][ks * 32 + g * 8]);
#pragma unroll
        for (int ot = 0; ot < 4; ot++) {
            bf16x8 bfr = ldb8(Wall + (ot * 16 + l15) * 256 + ks * 32 + g * 8);
            accqk[ot] = MFMA16(af, bfr, accqk[ot]);
        }
    }
#pragma unroll
    for (int ot = 0; ot < 4; ot++) {
        int o = ot * 16 + l15;
        float bias = ball[o];
#pragma unroll
        for (int r = 0; r < 4; r++) {
            int n = n0 + w * 16 + g * 4 + r;
            float v = accqk[ot][r] + bias;
            if (ot < 2) {
                qtg[((size_t)b * 4096 + n) * 32 + o] = f2b(v);
            } else {
                int c = o - 32;
                size_t idx = ((((size_t)b * 128 + (n >> 5)) * 2 + (c >> 4)) * 32
                              + (n & 31)) * 16 + (c & 15);
                ktg[idx] = f2b(v);
            }
        }
    }

    // --- v: D[o(256), n(64)], wave w owns o-tiles 4w..4w+3 ---
    f32x4 accv[4][4] = {};
#pragma unroll
    for (int ks = 0; ks < 8; ks++) {
        bf16x8 av[4], bv4[4];
#pragma unroll
        for (int mt = 0; mt < 4; mt++)
            av[mt] = ldb8(Wall + (64 + (w * 4 + mt) * 16 + l15) * 256 + ks * 32 + g * 8);
#pragma unroll
        for (int nt = 0; nt < 4; nt++)
            bv4[nt] = ldb8(&xt[nt * 16 + l15][ks * 32 + g * 8]);
#pragma unroll
        for (int mt = 0; mt < 4; mt++)
#pragma unroll
            for (int nt = 0; nt < 4; nt++)
                accv[mt][nt] = MFMA16(av[mt], bv4[nt], accv[mt][nt]);
    }
#pragma unroll
    for (int mt = 0; mt < 4; mt++) {
#pragma unroll
        for (int r = 0; r < 4; r++) {
            int o = (w * 4 + mt) * 16 + g * 4 + r;
            float bias = ball[64 + o];
#pragma unroll
            for (int nt = 0; nt < 4; nt++) {
                int n = n0 + nt * 16 + l15;
                size_t idx = (((size_t)b * 512 + (n >> 3)) * 256 + o) * 8 + (n & 7);
                vg[idx] = f2b(accv[mt][nt][r] + bias);
            }
        }
    }
}

// ---------------------------------------------------------------------------
// Kernel 2: flash attention v7b — barrier-free, LDS-free, 2 blocks/CU,
// 4-deep register ring prefetch, COALESCED K'/V' tile-packed layouts.
// grid 512 = b(4) x mtile(128) (32 m-rows), XCD-swizzled; 4 waves.
// ---------------------------------------------------------------------------
__global__ __launch_bounds__(256, 2) void attn_kernel(
    const uint16_t* __restrict__ qtg, const uint16_t* __restrict__ ktg,
    const uint16_t* __restrict__ vg, uint16_t* __restrict__ og) {
    __shared__ float ls[4][32];

    const int bid = blockIdx.x;
    const int swz = (bid & 7) * 64 + (bid >> 3);   // XCD-chunked (512%8==0)
    const int b = swz >> 7;
    const int m0 = (swz & 127) * 32;
    const int t = threadIdx.x, w = t >> 6, lane = t & 63;
    const int l31 = lane & 31, hi = lane >> 5;

    const uint16_t* qb = qtg + (size_t)b * 4096 * 32;
    const uint16_t* kb = ktg + (size_t)b * 131072;    // 128*2*32*16
    const uint16_t* vb = vg  + (size_t)b * 1048576;   // 512*256*8

    bf16x8 qf[2];
#pragma unroll
    for (int ks = 0; ks < 2; ks++)
        qf[ks] = ldb8(qb + (size_t)(m0 + l31) * 32 + ks * 16 + hi * 8);

    // K'[ch][ks][n32=l31][c16: hi*8]  -> kbase + ch*1024 + ks*512
    const uint16_t* kbase = kb + l31 * 16 + hi * 8;
    // V'[n8][c][8]: elem = n8*2048 + c*8 + n7; n8 = ch*4+ks*2+hi,
    // c = w*64+ct*32+l31  -> vbase + ch*8192 + ks*4096 + ct*256
    const uint16_t* vbase = vb + (size_t)hi * 2048 + (w * 64 + l31) * 8;

    f32x16 acc[2] = {};        // [ct]: O[m0+rows][w*64+ct*32+l31]
    float lpart = 0.f;

    auto loadK = [&](int ch, bf16x8* kf) {
#pragma unroll
        for (int ks = 0; ks < 2; ks++)
            kf[ks] = ldb8(kbase + ch * 1024 + ks * 512);
    };
    auto loadV = [&](int ch, bf16x8 (*vf)[2]) {
#pragma unroll
        for (int ct = 0; ct < 2; ct++)
#pragma unroll
            for (int ks = 0; ks < 2; ks++)
                vf[ct][ks] = ldb8(vbase + ch * 8192 + ks * 4096 + ct * 256);
    };

    auto step = [&](const bf16x8* kf, const bf16x8 (*vf)[2]) {
        f32x16 z = {};
        f32x16 s = MFMA32(kf[0], qf[0], z);
        s = MFMA32(kf[1], qf[1], s);
        // lane (l31,hi) reg r: n = (r&3)+8*(r>>2)+4*hi, m = m0+l31
        float e[16];
#pragma unroll
        for (int r = 0; r < 16; r++) e[r] = exp2_fast(s[r]);
        float sum = 0.f;
#pragma unroll
        for (int r = 0; r < 16; r++) sum += e[r];
        lpart += sum;

        bf16x8 paf[2];
#pragma unroll
        for (int ks = 0; ks < 2; ks++) {
            union { bf16x8 v; __bf16 h[8]; uint32_t d[4]; } u;
#pragma unroll
            for (int j = 0; j < 8; j++) u.h[j] = (__bf16)e[8 * ks + j];
            uint32_t g0 = hi ? u.d[0] : u.d[2];
            uint32_t g1 = hi ? u.d[1] : u.d[3];
            uint32_t r0 = (uint32_t)__shfl_xor((int)g0, 32);
            uint32_t r1 = (uint32_t)__shfl_xor((int)g1, 32);
            if (hi == 0) { u.d[2] = r0; u.d[3] = r1; }
            else         { u.d[0] = r0; u.d[1] = r1; }
            paf[ks] = u.v;
        }
#pragma unroll
        for (int ks = 0; ks < 2; ks++)
#pragma unroll
            for (int ct = 0; ct < 2; ct++)
                acc[ct] = MFMA32(paf[ks], vf[ct][ks], acc[ct]);
    };

    // 4-deep static ring buffer (all indices compile-time; rule #20)
    bf16x8 kf0[2], kf1[2], kf2[2], kf3[2];
    bf16x8 vf0[2][2], vf1[2][2], vf2[2][2], vf3[2][2];

    loadK(0, kf0); loadV(0, vf0);
    loadK(1, kf1); loadV(1, vf1);
    loadK(2, kf2); loadV(2, vf2);
    loadK(3, kf3); loadV(3, vf3);

    for (int ch = 0; ch < 124; ch += 4) {
        step(kf0, vf0); loadK(ch + 4, kf0); loadV(ch + 4, vf0);
        step(kf1, vf1); loadK(ch + 5, kf1); loadV(ch + 5, vf1);
        step(kf2, vf2); loadK(ch + 6, kf2); loadV(ch + 6, vf2);
        step(kf3, vf3); loadK(ch + 7, kf3); loadV(ch + 7, vf3);
    }
    step(kf0, vf0);
    step(kf1, vf1);
    step(kf2, vf2);
    step(kf3, vf3);

    // row-sum: lane (l31,hi) holds half of row m0+l31; combine across hi
    {
        float rs = lpart + __shfl_xor(lpart, 32);
        if (hi == 0) ls[w][l31] = 1.0f / rs;
    }
    __syncthreads();

#pragma unroll
    for (int r = 0; r < 16; r++) {
        const int rowm = (r & 3) + 8 * (r >> 2) + 4 * hi;
        const float rinv = ls[w][rowm];
        const size_t rowo = ((size_t)b * 4096 + m0 + rowm) * 256 + w * 64 + l31;
#pragma unroll
        for (int ct = 0; ct < 2; ct++)
            og[rowo + ct * 32] = f2b(acc[ct][r] * rinv);
    }
}

// ---------------------------------------------------------------------------
// Kernel 3: y = Wo[:, :256] @ out + Wo[:, 256:] @ x + bo.
// ---------------------------------------------------------------------------
__global__ __launch_bounds__(256) void out_kernel(
    const float* __restrict__ x, const uint16_t* __restrict__ og,
    const uint16_t* __restrict__ Wobf, const float* __restrict__ bo,
    float* __restrict__ y) {
    __shared__ uint16_t xt[64][264];

    const int b = blockIdx.x >> 6;
    const int m0 = (blockIdx.x & 63) * 64;
    const int t = threadIdx.x;
    const float* xb = x + (size_t)b * 256 * 4096;

    {
        const int nPart = t & 15, cIdx = t >> 4;
#pragma unroll
        for (int rep = 0; rep < 16; rep++) {
            int c = rep * 16 + cIdx;
            float4 f = *(const float4*)(xb + (size_t)c * 4096 + m0 + nPart * 4);
            xt[nPart * 4 + 0][c] = f2b(f.x);
            xt[nPart * 4 + 1][c] = f2b(f.y);
            xt[nPart * 4 + 2][c] = f2b(f.z);
            xt[nPart * 4 + 3][c] = f2b(f.w);
        }
    }
    __syncthreads();

    const int w = t >> 6, lane = t & 63, l15 = lane & 15, g = lane >> 4;
    const uint16_t* ob = og + ((size_t)b * 4096 + m0) * 256;

    f32x4 acc[4][4] = {};
#pragma unroll
    for (int ks = 0; ks < 8; ks++) {
        bf16x8 af[4], bfr[4];
#pragma unroll
        for (int mt = 0; mt < 4; mt++)
            af[mt] = ldb8(Wobf + ((w * 4 + mt) * 16 + l15) * 512 + ks * 32 + g * 8);
#pragma unroll
        for (int nt = 0; nt < 4; nt++)
            bfr[nt] = ldb8(ob + (size_t)(nt * 16 + l15) * 256 + ks * 32 + g * 8);
#pragma unroll
        for (int mt = 0; mt < 4; mt++)
#pragma unroll
            for (int nt = 0; nt < 4; nt++)
                acc[mt][nt] = MFMA16(af[mt], bfr[nt], acc[mt][nt]);
    }
#pragma unroll
    for (int ks = 0; ks < 8; ks++) {
        bf16x8 af[4], bfr[4];
#pragma unroll
        for (int mt = 0; mt < 4; mt++)
            af[mt] = ldb8(Wobf + ((w * 4 + mt) * 16 + l15) * 512 + 256 + ks * 32 + g * 8);
#pragma unroll
        for (int nt = 0; nt < 4; nt++)
            bfr[nt] = ldb8(&xt[nt * 16 + l15][ks * 32 + g * 8]);
#pragma unroll
        for (int mt = 0; mt < 4; mt++)
#pragma unroll
            for (int nt = 0; nt < 4; nt++)
                acc[mt][nt] = MFMA16(af[mt], bfr[nt], acc[mt][nt]);
    }

#pragma unroll
    for (int mt = 0; mt < 4; mt++)
#pragma unroll
        for (int r = 0; r < 4; r++) {
            int o = (w * 4 + mt) * 16 + g * 4 + r;
            float bias = bo[o];
#pragma unroll
            for (int nt = 0; nt < 4; nt++) {
                int m = m0 + nt * 16 + l15;
                y[((size_t)b * 256 + o) * 4096 + m] = acc[mt][nt][r] + bias;
            }
        }
}

// ---------------------------------------------------------------------------
extern "C" void kernel_launch(void* const* d_in, const int* in_sizes, int n_in,
                              void* d_out, int out_size, void* d_ws, size_t ws_size,
                              hipStream_t stream) {
    const float* x  = (const float*)d_in[0];
    const float* Wq = (const float*)d_in[1];
    const float* bq = (const float*)d_in[2];
    const float* Wk = (const float*)d_in[3];
    const float* bk = (const float*)d_in[4];
    const float* Wv = (const float*)d_in[5];
    const float* bv = (const float*)d_in[6];
    const float* Wo = (const float*)d_in[7];
    const float* bo = (const float*)d_in[8];
    float* y = (float*)d_out;

    char* ws = (char*)d_ws;
    uint16_t* Wall = (uint16_t*)(ws + 0);          // 163840 B
    uint16_t* Wobf = (uint16_t*)(ws + 163840);     // 262144 B
    float*    ball = (float*)(ws + 425984);        // 1280 B
    uint16_t* qtg  = (uint16_t*)(ws + 427520);     // 1 MiB
    uint16_t* ktg  = (uint16_t*)(ws + 1476096);    // 1 MiB
    uint16_t* vgw  = (uint16_t*)(ws + 2524672);    // 8 MiB
    uint16_t* ogw  = (uint16_t*)(ws + 10913280);   // 8 MiB

    pack_kernel<<<256, 256, 0, stream>>>(Wq, Wk, Wv, bq, bk, bv, Wo, Wall, Wobf, ball);
    qkv_kernel<<<256, 256, 0, stream>>>(x, Wall, ball, qtg, ktg, vgw);
    attn_kernel<<<512, 256, 0, stream>>>(qtg, ktg, vgw, ogw);
    out_kernel<<<256, 256, 0, stream>>>(x, ogw, Wobf, bo, y);
}

// Round 9
// 112.284 us; speedup vs baseline: 1.7183x; 1.1376x over previous
//
#include <hip/hip_runtime.h>
#include <stdint.h>

typedef __attribute__((ext_vector_type(8))) __bf16 bf16x8;
typedef __attribute__((ext_vector_type(4))) float f32x4;
typedef __attribute__((ext_vector_type(16))) float f32x16;

#define MFMA16(a, b, c) __builtin_amdgcn_mfma_f32_16x16x32_bf16((a), (b), (c), 0, 0, 0)
#define MFMA32(a, b, c) __builtin_amdgcn_mfma_f32_32x32x16_bf16((a), (b), (c), 0, 0, 0)

__device__ __forceinline__ uint16_t f2b(float f) {
    union { float f; uint32_t u; } v; v.f = f;
    uint32_t u = v.u;
    return (uint16_t)((u + 0x7FFFu + ((u >> 16) & 1u)) >> 16);
}

__device__ __forceinline__ bf16x8 ldb8(const uint16_t* p) {
    return *(const bf16x8*)p;
}

// exp2 as a compiler-visible intrinsic (hazard recognizer must see TRANS op).
__device__ __forceinline__ float exp2_fast(float x) {
#if __has_builtin(__builtin_amdgcn_exp2f)
    return __builtin_amdgcn_exp2f(x);
#else
    return __expf(x * 0.6931471805599453f);
#endif
}

// ---------------------------------------------------------------------------
// Kernel 0: pack weights to bf16.  Wall[320][256] = [Wq;Wk;Wv], ball[320],
// Wobf[256][512].  Wq/bq pre-scaled by log2(e) so attention uses exp2.
// ---------------------------------------------------------------------------
__global__ void pack_kernel(const float* __restrict__ Wq, const float* __restrict__ Wk,
                            const float* __restrict__ Wv, const float* __restrict__ bq,
                            const float* __restrict__ bk, const float* __restrict__ bv,
                            const float* __restrict__ Wo,
                            uint16_t* __restrict__ Wall, uint16_t* __restrict__ Wobf,
                            float* __restrict__ ball) {
    const float LOG2E = 1.4426950408889634f;
    int i = blockIdx.x * blockDim.x + threadIdx.x;
    int stride = gridDim.x * blockDim.x;
    for (int idx = i; idx < 320 * 256; idx += stride) {
        int r = idx >> 8, c = idx & 255;
        float v = (r < 32) ? Wq[r * 256 + c] * LOG2E
                 : (r < 64) ? Wk[(r - 32) * 256 + c]
                            : Wv[(r - 64) * 256 + c];
        Wall[idx] = f2b(v);
    }
    for (int idx = i; idx < 256 * 512; idx += stride) Wobf[idx] = f2b(Wo[idx]);
    for (int idx = i; idx < 320; idx += stride)
        ball[idx] = (idx < 32) ? bq[idx] * LOG2E
                  : (idx < 64) ? bk[idx - 32] : bv[idx - 64];
}

// ---------------------------------------------------------------------------
// Kernel 1: QKV projection.
// grid 256 = b(4) x ntile(64).  Emits:
//   qt[b][n][32]                       (k-contiguous rows)
//   K'[b][ch(128)][ks(2)][n32][c16]    (attn K-frag load = contiguous 1KB)
//   V'[b][n/8(512)][c(256)][n%8(8)]    (attn V-frag load = coalesced)
// ---------------------------------------------------------------------------
__global__ __launch_bounds__(256) void qkv_kernel(
    const float* __restrict__ x, const uint16_t* __restrict__ Wall,
    const float* __restrict__ ball, uint16_t* __restrict__ qtg,
    uint16_t* __restrict__ ktg, uint16_t* __restrict__ vg) {
    __shared__ uint16_t xt[64][264];   // [n_local][c], pad 264

    const int b = blockIdx.x >> 6;
    const int n0 = (blockIdx.x & 63) * 64;
    const int t = threadIdx.x;
    const float* xb = x + (size_t)b * 256 * 4096;

    {
        const int nPart = t & 15, cIdx = t >> 4;
#pragma unroll
        for (int rep = 0; rep < 16; rep++) {
            int c = rep * 16 + cIdx;
            float4 f = *(const float4*)(xb + (size_t)c * 4096 + n0 + nPart * 4);
            xt[nPart * 4 + 0][c] = f2b(f.x);
            xt[nPart * 4 + 1][c] = f2b(f.y);
            xt[nPart * 4 + 2][c] = f2b(f.z);
            xt[nPart * 4 + 3][c] = f2b(f.w);
        }
    }
    __syncthreads();

    const int w = t >> 6, lane = t & 63, l15 = lane & 15, g = lane >> 4;

    // --- qk: D[n(64), o(64)], wave w owns m-tile w ---
    f32x4 accqk[4] = {};
#pragma unroll
    for (int ks = 0; ks < 8; ks++) {
        bf16x8 af = ldb8(&xt[w * 16 + l15][ks * 32 + g * 8]);
#pragma unroll
        for (int ot = 0; ot < 4; ot++) {
            bf16x8 bfr = ldb8(Wall + (ot * 16 + l15) * 256 + ks * 32 + g * 8);
            accqk[ot] = MFMA16(af, bfr, accqk[ot]);
        }
    }
#pragma unroll
    for (int ot = 0; ot < 4; ot++) {
        int o = ot * 16 + l15;
        float bias = ball[o];
#pragma unroll
        for (int r = 0; r < 4; r++) {
            int n = n0 + w * 16 + g * 4 + r;
            float v = accqk[ot][r] + bias;
            if (ot < 2) {
                qtg[((size_t)b * 4096 + n) * 32 + o] = f2b(v);
            } else {
                int c = o - 32;
                size_t idx = ((((size_t)b * 128 + (n >> 5)) * 2 + (c >> 4)) * 32
                              + (n & 31)) * 16 + (c & 15);
                ktg[idx] = f2b(v);
            }
        }
    }

    // --- v: D[o(256), n(64)], wave w owns o-tiles 4w..4w+3 ---
    f32x4 accv[4][4] = {};
#pragma unroll
    for (int ks = 0; ks < 8; ks++) {
        bf16x8 av[4], bv4[4];
#pragma unroll
        for (int mt = 0; mt < 4; mt++)
            av[mt] = ldb8(Wall + (64 + (w * 4 + mt) * 16 + l15) * 256 + ks * 32 + g * 8);
#pragma unroll
        for (int nt = 0; nt < 4; nt++)
            bv4[nt] = ldb8(&xt[nt * 16 + l15][ks * 32 + g * 8]);
#pragma unroll
        for (int mt = 0; mt < 4; mt++)
#pragma unroll
            for (int nt = 0; nt < 4; nt++)
                accv[mt][nt] = MFMA16(av[mt], bv4[nt], accv[mt][nt]);
    }
#pragma unroll
    for (int mt = 0; mt < 4; mt++) {
#pragma unroll
        for (int r = 0; r < 4; r++) {
            int o = (w * 4 + mt) * 16 + g * 4 + r;
            float bias = ball[64 + o];
#pragma unroll
            for (int nt = 0; nt < 4; nt++) {
                int n = n0 + nt * 16 + l15;
                size_t idx = (((size_t)b * 512 + (n >> 3)) * 256 + o) * 8 + (n & 7);
                vg[idx] = f2b(accv[mt][nt][r] + bias);
            }
        }
    }
}

// ---------------------------------------------------------------------------
// Kernel 2: flash attention v8 — barrier-free main loop, 2x2 wave split.
// grid 512 = b(4) x mtile(128) (32 m-rows), XCD-swizzled; 4 waves.
// Wave (cw = w>>1, nw = w&1): cw owns channels [cw*128, cw*128+128),
// nw owns chunks ch = 2i+nw (i=0..63).  Softmax+QK^T redundancy 4x -> 2x.
// Epilogue: nw=1 waves stage partial O + row-sums in LDS; one barrier;
// nw=0 waves combine, scale by 1/(l0+l1), store.
// ---------------------------------------------------------------------------
__global__ __launch_bounds__(256, 2) void attn_kernel(
    const uint16_t* __restrict__ qtg, const uint16_t* __restrict__ ktg,
    const uint16_t* __restrict__ vg, uint16_t* __restrict__ og) {
    __shared__ float ls[4][32];
    __shared__ float po[2][128][36];   // [cw][cLocal][m], pad 36 (16B rows, 4-way)

    const int bid = blockIdx.x;
    const int swz = (bid & 7) * 64 + (bid >> 3);   // XCD-chunked (512%8==0)
    const int b = swz >> 7;
    const int m0 = (swz & 127) * 32;
    const int t = threadIdx.x, w = t >> 6, lane = t & 63;
    const int l31 = lane & 31, hi = lane >> 5;
    const int cw = w >> 1, nw = w & 1;

    const uint16_t* qb = qtg + (size_t)b * 4096 * 32;
    const uint16_t* kb = ktg + (size_t)b * 131072;    // 128*2*32*16
    const uint16_t* vb = vg  + (size_t)b * 1048576;   // 512*256*8

    bf16x8 qf[2];
#pragma unroll
    for (int ks = 0; ks < 2; ks++)
        qf[ks] = ldb8(qb + (size_t)(m0 + l31) * 32 + ks * 16 + hi * 8);

    // K'[ch][ks][n32=l31][c16: hi*8]  -> kbase + ch*1024 + ks*512
    const uint16_t* kbase = kb + l31 * 16 + hi * 8;
    // V'[n8][c][8]: elem = n8*2048 + c*8 + n7; n8 = ch*4+ks*2+hi,
    // c = cw*128+ct*32+l31  -> vbase + ch*8192 + ks*4096 + ct*256
    const uint16_t* vbase = vb + (size_t)hi * 2048 + (cw * 128 + l31) * 8;

    f32x16 acc[4] = {};        // [ct]: partial O[m0+rows][cw*128+ct*32+l31]
    float lpart = 0.f;

    auto loadK = [&](int ch, bf16x8* kf) {
#pragma unroll
        for (int ks = 0; ks < 2; ks++)
            kf[ks] = ldb8(kbase + ch * 1024 + ks * 512);
    };
    auto loadV = [&](int ch, bf16x8 (*vf)[2]) {
#pragma unroll
        for (int ct = 0; ct < 4; ct++)
#pragma unroll
            for (int ks = 0; ks < 2; ks++)
                vf[ct][ks] = ldb8(vbase + ch * 8192 + ks * 4096 + ct * 256);
    };

    auto step = [&](const bf16x8* kf, const bf16x8 (*vf)[2]) {
        f32x16 z = {};
        f32x16 s = MFMA32(kf[0], qf[0], z);
        s = MFMA32(kf[1], qf[1], s);
        // lane (l31,hi) reg r: n = (r&3)+8*(r>>2)+4*hi, m = m0+l31
        float e[16];
#pragma unroll
        for (int r = 0; r < 16; r++) e[r] = exp2_fast(s[r]);
        float sum = 0.f;
#pragma unroll
        for (int r = 0; r < 16; r++) sum += e[r];
        lpart += sum;

        bf16x8 paf[2];
#pragma unroll
        for (int ks = 0; ks < 2; ks++) {
            union { bf16x8 v; __bf16 h[8]; uint32_t d[4]; } u;
#pragma unroll
            for (int j = 0; j < 8; j++) u.h[j] = (__bf16)e[8 * ks + j];
            uint32_t g0 = hi ? u.d[0] : u.d[2];
            uint32_t g1 = hi ? u.d[1] : u.d[3];
            uint32_t r0 = (uint32_t)__shfl_xor((int)g0, 32);
            uint32_t r1 = (uint32_t)__shfl_xor((int)g1, 32);
            if (hi == 0) { u.d[2] = r0; u.d[3] = r1; }
            else         { u.d[0] = r0; u.d[1] = r1; }
            paf[ks] = u.v;
        }
#pragma unroll
        for (int ks = 0; ks < 2; ks++)
#pragma unroll
            for (int ct = 0; ct < 4; ct++)
                acc[ct] = MFMA32(paf[ks], vf[ct][ks], acc[ct]);
    };

    // 2-deep ring over this wave's chunks (ch = 2i + nw)
    bf16x8 kfA[2], kfB[2], vfA[4][2], vfB[4][2];
    loadK(nw, kfA);     loadV(nw, vfA);
    loadK(nw + 2, kfB); loadV(nw + 2, vfB);

    for (int it = 0; it < 64; it += 2) {
        step(kfA, vfA);
        if (it + 2 < 64) { loadK(nw + 2 * (it + 2), kfA); loadV(nw + 2 * (it + 2), vfA); }
        step(kfB, vfB);
        if (it + 3 < 64) { loadK(nw + 2 * (it + 3), kfB); loadV(nw + 2 * (it + 3), vfB); }
    }

    // ---- epilogue: cross-nw reduction ----
    {
        float rs = lpart + __shfl_xor(lpart, 32);
        if (hi == 0) ls[w][l31] = rs;          // raw partial row sums
    }
    if (nw == 1) {
#pragma unroll
        for (int ct = 0; ct < 4; ct++)
#pragma unroll
            for (int rq = 0; rq < 4; rq++) {
                f32x4 v4;
                v4[0] = acc[ct][4 * rq + 0];
                v4[1] = acc[ct][4 * rq + 1];
                v4[2] = acc[ct][4 * rq + 2];
                v4[3] = acc[ct][4 * rq + 3];
                *(f32x4*)&po[cw][ct * 32 + l31][8 * rq + 4 * hi] = v4;
            }
    }
    __syncthreads();

    if (nw == 0) {
#pragma unroll
        for (int ct = 0; ct < 4; ct++) {
#pragma unroll
            for (int rq = 0; rq < 4; rq++) {
                f32x4 p4 = *(const f32x4*)&po[cw][ct * 32 + l31][8 * rq + 4 * hi];
#pragma unroll
                for (int j = 0; j < 4; j++) {
                    const int r = 4 * rq + j;
                    const int rowm = (r & 3) + 8 * (r >> 2) + 4 * hi;
                    const float l = ls[cw * 2][rowm] + ls[cw * 2 + 1][rowm];
                    const float tot = (acc[ct][r] + p4[j]) / l;
                    const size_t idx = ((size_t)b * 4096 + m0 + rowm) * 256
                                     + cw * 128 + ct * 32 + l31;
                    og[idx] = f2b(tot);
                }
            }
        }
    }
}

// ---------------------------------------------------------------------------
// Kernel 3: y = Wo[:, :256] @ out + Wo[:, 256:] @ x + bo.
// ---------------------------------------------------------------------------
__global__ __launch_bounds__(256) void out_kernel(
    const float* __restrict__ x, const uint16_t* __restrict__ og,
    const uint16_t* __restrict__ Wobf, const float* __restrict__ bo,
    float* __restrict__ y) {
    __shared__ uint16_t xt[64][264];

    const int b = blockIdx.x >> 6;
    const int m0 = (blockIdx.x & 63) * 64;
    const int t = threadIdx.x;
    const float* xb = x + (size_t)b * 256 * 4096;

    {
        const int nPart = t & 15, cIdx = t >> 4;
#pragma unroll
        for (int rep = 0; rep < 16; rep++) {
            int c = rep * 16 + cIdx;
            float4 f = *(const float4*)(xb + (size_t)c * 4096 + m0 + nPart * 4);
            xt[nPart * 4 + 0][c] = f2b(f.x);
            xt[nPart * 4 + 1][c] = f2b(f.y);
            xt[nPart * 4 + 2][c] = f2b(f.z);
            xt[nPart * 4 + 3][c] = f2b(f.w);
        }
    }
    __syncthreads();

    const int w = t >> 6, lane = t & 63, l15 = lane & 15, g = lane >> 4;
    const uint16_t* ob = og + ((size_t)b * 4096 + m0) * 256;

    f32x4 acc[4][4] = {};
#pragma unroll
    for (int ks = 0; ks < 8; ks++) {
        bf16x8 af[4], bfr[4];
#pragma unroll
        for (int mt = 0; mt < 4; mt++)
            af[mt] = ldb8(Wobf + ((w * 4 + mt) * 16 + l15) * 512 + ks * 32 + g * 8);
#pragma unroll
        for (int nt = 0; nt < 4; nt++)
            bfr[nt] = ldb8(ob + (size_t)(nt * 16 + l15) * 256 + ks * 32 + g * 8);
#pragma unroll
        for (int mt = 0; mt < 4; mt++)
#pragma unroll
            for (int nt = 0; nt < 4; nt++)
                acc[mt][nt] = MFMA16(af[mt], bfr[nt], acc[mt][nt]);
    }
#pragma unroll
    for (int ks = 0; ks < 8; ks++) {
        bf16x8 af[4], bfr[4];
#pragma unroll
        for (int mt = 0; mt < 4; mt++)
            af[mt] = ldb8(Wobf + ((w * 4 + mt) * 16 + l15) * 512 + 256 + ks * 32 + g * 8);
#pragma unroll
        for (int nt = 0; nt < 4; nt++)
            bfr[nt] = ldb8(&xt[nt * 16 + l15][ks * 32 + g * 8]);
#pragma unroll
        for (int mt = 0; mt < 4; mt++)
#pragma unroll
            for (int nt = 0; nt < 4; nt++)
                acc[mt][nt] = MFMA16(af[mt], bfr[nt], acc[mt][nt]);
    }

#pragma unroll
    for (int mt = 0; mt < 4; mt++)
#pragma unroll
        for (int r = 0; r < 4; r++) {
            int o = (w * 4 + mt) * 16 + g * 4 + r;
            float bias = bo[o];
#pragma unroll
            for (int nt = 0; nt < 4; nt++) {
                int m = m0 + nt * 16 + l15;
                y[((size_t)b * 256 + o) * 4096 + m] = acc[mt][nt][r] + bias;
            }
        }
}

// ---------------------------------------------------------------------------
extern "C" void kernel_launch(void* const* d_in, const int* in_sizes, int n_in,
                              void* d_out, int out_size, void* d_ws, size_t ws_size,
                              hipStream_t stream) {
    const float* x  = (const float*)d_in[0];
    const float* Wq = (const float*)d_in[1];
    const float* bq = (const float*)d_in[2];
    const float* Wk = (const float*)d_in[3];
    const float* bk = (const float*)d_in[4];
    const float* Wv = (const float*)d_in[5];
    const float* bv = (const float*)d_in[6];
    const float* Wo = (const float*)d_in[7];
    const float* bo = (const float*)d_in[8];
    float* y = (float*)d_out;

    char* ws = (char*)d_ws;
    uint16_t* Wall = (uint16_t*)(ws + 0);          // 163840 B
    uint16_t* Wobf = (uint16_t*)(ws + 163840);     // 262144 B
    float*    ball = (float*)(ws + 425984);        // 1280 B
    uint16_t* qtg  = (uint16_t*)(ws + 427520);     // 1 MiB
    uint16_t* ktg  = (uint16_t*)(ws + 1476096);    // 1 MiB
    uint16_t* vgw  = (uint16_t*)(ws + 2524672);    // 8 MiB
    uint16_t* ogw  = (uint16_t*)(ws + 10913280);   // 8 MiB

    pack_kernel<<<256, 256, 0, stream>>>(Wq, Wk, Wv, bq, bk, bv, Wo, Wall, Wobf, ball);
    qkv_kernel<<<256, 256, 0, stream>>>(x, Wall, ball, qtg, ktg, vgw);
    attn_kernel<<<512, 256, 0, stream>>>(qtg, ktg, vgw, ogw);
    out_kernel<<<256, 256, 0, stream>>>(x, ogw, Wobf, bo, y);
}

// Round 10
// 102.558 us; speedup vs baseline: 1.8813x; 1.0948x over previous
//
#include <hip/hip_runtime.h>
#include <stdint.h>

typedef __attribute__((ext_vector_type(8))) __bf16 bf16x8;
typedef __attribute__((ext_vector_type(4))) float f32x4;
typedef __attribute__((ext_vector_type(16))) float f32x16;

#define MFMA16(a, b, c) __builtin_amdgcn_mfma_f32_16x16x32_bf16((a), (b), (c), 0, 0, 0)
#define MFMA32(a, b, c) __builtin_amdgcn_mfma_f32_32x32x16_bf16((a), (b), (c), 0, 0, 0)

__device__ __forceinline__ uint16_t f2b(float f) {
    union { float f; uint32_t u; } v; v.f = f;
    uint32_t u = v.u;
    return (uint16_t)((u + 0x7FFFu + ((u >> 16) & 1u)) >> 16);
}

__device__ __forceinline__ bf16x8 ldb8(const uint16_t* p) {
    return *(const bf16x8*)p;
}

// exp2 as a compiler-visible intrinsic (hazard recognizer must see TRANS op).
__device__ __forceinline__ float exp2_fast(float x) {
#if __has_builtin(__builtin_amdgcn_exp2f)
    return __builtin_amdgcn_exp2f(x);
#else
    return __expf(x * 0.6931471805599453f);
#endif
}

// ---------------------------------------------------------------------------
// Kernel 0: pack weights to bf16.  Wall[320][256] = [Wq;Wk;Wv], ball[320],
// Wobf[256][512].  Wq/bq pre-scaled by log2(e) so attention uses exp2.
// ---------------------------------------------------------------------------
__global__ void pack_kernel(const float* __restrict__ Wq, const float* __restrict__ Wk,
                            const float* __restrict__ Wv, const float* __restrict__ bq,
                            const float* __restrict__ bk, const float* __restrict__ bv,
                            const float* __restrict__ Wo,
                            uint16_t* __restrict__ Wall, uint16_t* __restrict__ Wobf,
                            float* __restrict__ ball) {
    const float LOG2E = 1.4426950408889634f;
    int i = blockIdx.x * blockDim.x + threadIdx.x;
    int stride = gridDim.x * blockDim.x;
    for (int idx = i; idx < 320 * 256; idx += stride) {
        int r = idx >> 8, c = idx & 255;
        float v = (r < 32) ? Wq[r * 256 + c] * LOG2E
                 : (r < 64) ? Wk[(r - 32) * 256 + c]
                            : Wv[(r - 64) * 256 + c];
        Wall[idx] = f2b(v);
    }
    for (int idx = i; idx < 256 * 512; idx += stride) Wobf[idx] = f2b(Wo[idx]);
    for (int idx = i; idx < 320; idx += stride)
        ball[idx] = (idx < 32) ? bq[idx] * LOG2E
                  : (idx < 64) ? bk[idx - 32] : bv[idx - 64];
}

// ---------------------------------------------------------------------------
// Kernel 1: QKV projection.
// grid 256 = b(4) x ntile(64).  Emits:
//   qt[b][n][32]                       (k-contiguous rows)
//   K'[b][ch(128)][ks(2)][n32][c16]    (attn K-frag load = contiguous)
//   V'[b][n/8(512)][c(256)][n%8(8)]    (attn V-frag load = coalesced)
// ---------------------------------------------------------------------------
__global__ __launch_bounds__(256) void qkv_kernel(
    const float* __restrict__ x, const uint16_t* __restrict__ Wall,
    const float* __restrict__ ball, uint16_t* __restrict__ qtg,
    uint16_t* __restrict__ ktg, uint16_t* __restrict__ vg) {
    __shared__ uint16_t xt[64][264];   // [n_local][c], pad 264

    const int b = blockIdx.x >> 6;
    const int n0 = (blockIdx.x & 63) * 64;
    const int t = threadIdx.x;
    const float* xb = x + (size_t)b * 256 * 4096;

    {
        const int nPart = t & 15, cIdx = t >> 4;
#pragma unroll
        for (int rep = 0; rep < 16; rep++) {
            int c = rep * 16 + cIdx;
            float4 f = *(const float4*)(xb + (size_t)c * 4096 + n0 + nPart * 4);
            xt[nPart * 4 + 0][c] = f2b(f.x);
            xt[nPart * 4 + 1][c] = f2b(f.y);
            xt[nPart * 4 + 2][c] = f2b(f.z);
            xt[nPart * 4 + 3][c] = f2b(f.w);
        }
    }
    __syncthreads();

    const int w = t >> 6, lane = t & 63, l15 = lane & 15, g = lane >> 4;

    // --- qk: D[n(64), o(64)], wave w owns m-tile w ---
    f32x4 accqk[4] = {};
#pragma unroll
    for (int ks = 0; ks < 8; ks++) {
        bf16x8 af = ldb8(&xt[w * 16 + l15][ks * 32 + g * 8]);
#pragma unroll
        for (int ot = 0; ot < 4; ot++) {
            bf16x8 bfr = ldb8(Wall + (ot * 16 + l15) * 256 + ks * 32 + g * 8);
            accqk[ot] = MFMA16(af, bfr, accqk[ot]);
        }
    }
#pragma unroll
    for (int ot = 0; ot < 4; ot++) {
        int o = ot * 16 + l15;
        float bias = ball[o];
#pragma unroll
        for (int r = 0; r < 4; r++) {
            int n = n0 + w * 16 + g * 4 + r;
            float v = accqk[ot][r] + bias;
            if (ot < 2) {
                qtg[((size_t)b * 4096 + n) * 32 + o] = f2b(v);
            } else {
                int c = o - 32;
                size_t idx = ((((size_t)b * 128 + (n >> 5)) * 2 + (c >> 4)) * 32
                              + (n & 31)) * 16 + (c & 15);
                ktg[idx] = f2b(v);
            }
        }
    }

    // --- v: D[o(256), n(64)], wave w owns o-tiles 4w..4w+3 ---
    f32x4 accv[4][4] = {};
#pragma unroll
    for (int ks = 0; ks < 8; ks++) {
        bf16x8 av[4], bv4[4];
#pragma unroll
        for (int mt = 0; mt < 4; mt++)
            av[mt] = ldb8(Wall + (64 + (w * 4 + mt) * 16 + l15) * 256 + ks * 32 + g * 8);
#pragma unroll
        for (int nt = 0; nt < 4; nt++)
            bv4[nt] = ldb8(&xt[nt * 16 + l15][ks * 32 + g * 8]);
#pragma unroll
        for (int mt = 0; mt < 4; mt++)
#pragma unroll
            for (int nt = 0; nt < 4; nt++)
                accv[mt][nt] = MFMA16(av[mt], bv4[nt], accv[mt][nt]);
    }
#pragma unroll
    for (int mt = 0; mt < 4; mt++) {
#pragma unroll
        for (int r = 0; r < 4; r++) {
            int o = (w * 4 + mt) * 16 + g * 4 + r;
            float bias = ball[64 + o];
#pragma unroll
            for (int nt = 0; nt < 4; nt++) {
                int n = n0 + nt * 16 + l15;
                size_t idx = (((size_t)b * 512 + (n >> 3)) * 256 + o) * 8 + (n & 7);
                vg[idx] = f2b(accv[mt][nt][r] + bias);
            }
        }
    }
}

// ---------------------------------------------------------------------------
// Kernel 2: flash attention v9 — cooperative S production (no redundancy).
// grid 512 = b(4) x mtile(128) (32 m-rows), XCD-swizzled; 4 waves, 2 blk/CU.
// All waves process the SAME chunk.  Wave w = (mh = w>>1, nhf = w&1):
// S quarter [16m x 16n] via one MFMA16(K,Q); 4 exp; P -> 2KB double-buffered
// XOR-swizzled LDS tile (ds_write_b64).  One barrier per chunk, then each
// wave PVs its 64-channel slice (pa from LDS, 4 MFMA32).  Row sums: per-lane
// partials, reduced in epilogue.
// ---------------------------------------------------------------------------
__global__ __launch_bounds__(256, 2) void attn_kernel(
    const uint16_t* __restrict__ qtg, const uint16_t* __restrict__ ktg,
    const uint16_t* __restrict__ vg, uint16_t* __restrict__ og) {
    __shared__ uint16_t pts[2][32][32];   // P double buffer, swizzled quads
    __shared__ float lsp[4][16];          // per-wave partial row sums

    const int bid = blockIdx.x;
    const int swz = (bid & 7) * 64 + (bid >> 3);   // XCD-chunked (512%8==0)
    const int b = swz >> 7;
    const int m0 = (swz & 127) * 32;
    const int t = threadIdx.x, w = t >> 6, lane = t & 63;
    const int l15 = lane & 15, g = lane >> 4;
    const int l31 = lane & 31, hi = lane >> 5;
    const int mh = w >> 1, nhf = w & 1;

    const uint16_t* qb = qtg + (size_t)b * 4096 * 32;
    const uint16_t* kb = ktg + (size_t)b * 131072;    // 128*2*32*16
    const uint16_t* vb = vg  + (size_t)b * 1048576;   // 512*256*8

    // S-producer fragments: A = K rows (n), B = Q rows (m), K-dim = c(32)
    const bf16x8 qf = ldb8(qb + (size_t)(m0 + mh * 16 + l15) * 32 + g * 8);
    const uint16_t* kbase = kb + (g >> 1) * 512 + (nhf * 16 + l15) * 16 + (g & 1) * 8;

    // P write address (constant per lane): row m_loc, quad wq, swizzled
    const int m_loc = mh * 16 + l15;
    const int wq = nhf * 4 + g;                       // n-quad index 0..7
    char* const pwr = (char*)pts + m_loc * 64 + ((wq ^ (m_loc & 7)) * 8);

    // pa read addresses (constant per lane): row l31, quads q0,q0+1 per ks
    int prd[2][2];
#pragma unroll
    for (int ks = 0; ks < 2; ks++) {
        int q0 = ks * 4 + hi * 2;
        prd[ks][0] = l31 * 64 + ((q0 ^ (l31 & 7)) * 8);
        prd[ks][1] = l31 * 64 + (((q0 + 1) ^ (l31 & 7)) * 8);
    }

    // V base: V'[n8][c][8], n8 = ch*4 + ks*2 + hi, c = w*64 + ct*32 + l31
    const uint16_t* vbase = vb + (size_t)hi * 2048 + (w * 64 + l31) * 8;

    f32x16 acc[2] = {};        // [ct]: O[m0..+32][w*64 + ct*32 + l31]
    float lpart = 0.f;

    auto loadK = [&](int ch) -> bf16x8 { return ldb8(kbase + ch * 1024); };
    auto loadV = [&](int ch, bf16x8 (*vf)[2]) {
#pragma unroll
        for (int ct = 0; ct < 2; ct++)
#pragma unroll
            for (int ks = 0; ks < 2; ks++)
                vf[ct][ks] = ldb8(vbase + ch * 8192 + ks * 4096 + ct * 256);
    };

    auto sphase = [&](const bf16x8 kf, char* bufb) {
        f32x4 z = {};
        f32x4 s = MFMA16(kf, qf, z);
        // lane (l15,g) reg r: m = m0+mh*16+l15, n = ch*32 + nhf*16 + g*4 + r
        float e0 = exp2_fast(s[0]), e1 = exp2_fast(s[1]);
        float e2 = exp2_fast(s[2]), e3 = exp2_fast(s[3]);
        lpart += (e0 + e1) + (e2 + e3);
        union { uint2 d; __bf16 h[4]; } u;
        u.h[0] = (__bf16)e0; u.h[1] = (__bf16)e1;
        u.h[2] = (__bf16)e2; u.h[3] = (__bf16)e3;
        *(uint2*)(bufb) = u.d;
    };
    auto pv = [&](const char* bufc, const bf16x8 (*vf)[2]) {
        bf16x8 pa[2];
#pragma unroll
        for (int ks = 0; ks < 2; ks++) {
            union { bf16x8 v; uint2 dd[2]; } up;
            up.dd[0] = *(const uint2*)(bufc + prd[ks][0]);
            up.dd[1] = *(const uint2*)(bufc + prd[ks][1]);
            pa[ks] = up.v;
        }
#pragma unroll
        for (int ks = 0; ks < 2; ks++)
#pragma unroll
            for (int ct = 0; ct < 2; ct++)
                acc[ct] = MFMA32(pa[ks], vf[ct][ks], acc[ct]);
    };

    char* const buf0 = (char*)pts;
    char* const buf1 = (char*)pts + 2048;

    bf16x8 kfA = loadK(0), kfB = loadK(1);
    bf16x8 vfA[2][2], vfB[2][2];
    loadV(0, vfA);
    loadV(1, vfB);

    for (int it = 0; it < 128; it += 2) {
        // even chunk -> P buf0
        sphase(kfA, pwr);                       // pwr is inside buf0 region
        if (it + 2 < 128) kfA = loadK(it + 2);
        __syncthreads();
        pv(buf0, vfA);
        if (it + 2 < 128) loadV(it + 2, vfA);
        // odd chunk -> P buf1
        sphase(kfB, pwr + 2048);
        if (it + 3 < 128) kfB = loadK(it + 3);
        __syncthreads();
        pv(buf1, vfB);
        if (it + 3 < 128) loadV(it + 3, vfB);
    }

    // ---- epilogue: row sums ----
    lpart += __shfl_xor(lpart, 16);
    lpart += __shfl_xor(lpart, 32);
    if (lane < 16) lsp[w][lane] = lpart;        // partial for m=mh*16+lane, n-half nhf
    __syncthreads();

#pragma unroll
    for (int r = 0; r < 16; r++) {
        const int m = (r & 3) + 8 * (r >> 2) + 4 * hi;
        const float l = lsp[2 * (m >> 4)][m & 15] + lsp[2 * (m >> 4) + 1][m & 15];
        const float rinv = 1.0f / l;
        const size_t rowo = ((size_t)b * 4096 + m0 + m) * 256 + w * 64 + l31;
        og[rowo] = f2b(acc[0][r] * rinv);
        og[rowo + 32] = f2b(acc[1][r] * rinv);
    }
}

// ---------------------------------------------------------------------------
// Kernel 3: y = Wo[:, :256] @ out + Wo[:, 256:] @ x + bo.
// ---------------------------------------------------------------------------
__global__ __launch_bounds__(256) void out_kernel(
    const float* __restrict__ x, const uint16_t* __restrict__ og,
    const uint16_t* __restrict__ Wobf, const float* __restrict__ bo,
    float* __restrict__ y) {
    __shared__ uint16_t xt[64][264];

    const int b = blockIdx.x >> 6;
    const int m0 = (blockIdx.x & 63) * 64;
    const int t = threadIdx.x;
    const float* xb = x + (size_t)b * 256 * 4096;

    {
        const int nPart = t & 15, cIdx = t >> 4;
#pragma unroll
        for (int rep = 0; rep < 16; rep++) {
            int c = rep * 16 + cIdx;
            float4 f = *(const float4*)(xb + (size_t)c * 4096 + m0 + nPart * 4);
            xt[nPart * 4 + 0][c] = f2b(f.x);
            xt[nPart * 4 + 1][c] = f2b(f.y);
            xt[nPart * 4 + 2][c] = f2b(f.z);
            xt[nPart * 4 + 3][c] = f2b(f.w);
        }
    }
    __syncthreads();

    const int w = t >> 6, lane = t & 63, l15 = lane & 15, g = lane >> 4;
    const uint16_t* ob = og + ((size_t)b * 4096 + m0) * 256;

    f32x4 acc[4][4] = {};
#pragma unroll
    for (int ks = 0; ks < 8; ks++) {
        bf16x8 af[4], bfr[4];
#pragma unroll
        for (int mt = 0; mt < 4; mt++)
            af[mt] = ldb8(Wobf + ((w * 4 + mt) * 16 + l15) * 512 + ks * 32 + g * 8);
#pragma unroll
        for (int nt = 0; nt < 4; nt++)
            bfr[nt] = ldb8(ob + (size_t)(nt * 16 + l15) * 256 + ks * 32 + g * 8);
#pragma unroll
        for (int mt = 0; mt < 4; mt++)
#pragma unroll
            for (int nt = 0; nt < 4; nt++)
                acc[mt][nt] = MFMA16(af[mt], bfr[nt], acc[mt][nt]);
    }
#pragma unroll
    for (int ks = 0; ks < 8; ks++) {
        bf16x8 af[4], bfr[4];
#pragma unroll
        for (int mt = 0; mt < 4; mt++)
            af[mt] = ldb8(Wobf + ((w * 4 + mt) * 16 + l15) * 512 + 256 + ks * 32 + g * 8);
#pragma unroll
        for (int nt = 0; nt < 4; nt++)
            bfr[nt] = ldb8(&xt[nt * 16 + l15][ks * 32 + g * 8]);
#pragma unroll
        for (int mt = 0; mt < 4; mt++)
#pragma unroll
            for (int nt = 0; nt < 4; nt++)
                acc[mt][nt] = MFMA16(af[mt], bfr[nt], acc[mt][nt]);
    }

#pragma unroll
    for (int mt = 0; mt < 4; mt++)
#pragma unroll
        for (int r = 0; r < 4; r++) {
            int o = (w * 4 + mt) * 16 + g * 4 + r;
            float bias = bo[o];
#pragma unroll
            for (int nt = 0; nt < 4; nt++) {
                int m = m0 + nt * 16 + l15;
                y[((size_t)b * 256 + o) * 4096 + m] = acc[mt][nt][r] + bias;
            }
        }
}

// ---------------------------------------------------------------------------
extern "C" void kernel_launch(void* const* d_in, const int* in_sizes, int n_in,
                              void* d_out, int out_size, void* d_ws, size_t ws_size,
                              hipStream_t stream) {
    const float* x  = (const float*)d_in[0];
    const float* Wq = (const float*)d_in[1];
    const float* bq = (const float*)d_in[2];
    const float* Wk = (const float*)d_in[3];
    const float* bk = (const float*)d_in[4];
    const float* Wv = (const float*)d_in[5];
    const float* bv = (const float*)d_in[6];
    const float* Wo = (const float*)d_in[7];
    const float* bo = (const float*)d_in[8];
    float* y = (float*)d_out;

    char* ws = (char*)d_ws;
    uint16_t* Wall = (uint16_t*)(ws + 0);          // 163840 B
    uint16_t* Wobf = (uint16_t*)(ws + 163840);     // 262144 B
    float*    ball = (float*)(ws + 425984);        // 1280 B
    uint16_t* qtg  = (uint16_t*)(ws + 427520);     // 1 MiB
    uint16_t* ktg  = (uint16_t*)(ws + 1476096);    // 1 MiB
    uint16_t* vgw  = (uint16_t*)(ws + 2524672);    // 8 MiB
    uint16_t* ogw  = (uint16_t*)(ws + 10913280);   // 8 MiB

    pack_kernel<<<256, 256, 0, stream>>>(Wq, Wk, Wv, bq, bk, bv, Wo, Wall, Wobf, ball);
    qkv_kernel<<<256, 256, 0, stream>>>(x, Wall, ball, qtg, ktg, vgw);
    attn_kernel<<<512, 256, 0, stream>>>(qtg, ktg, vgw, ogw);
    out_kernel<<<256, 256, 0, stream>>>(x, ogw, Wobf, bo, y);
}

// Round 11
// 101.715 us; speedup vs baseline: 1.8969x; 1.0083x over previous
//
#include <hip/hip_runtime.h>
#include <stdint.h>

typedef __attribute__((ext_vector_type(8))) __bf16 bf16x8;
typedef __attribute__((ext_vector_type(4))) float f32x4;
typedef __attribute__((ext_vector_type(16))) float f32x16;

#define MFMA16(a, b, c) __builtin_amdgcn_mfma_f32_16x16x32_bf16((a), (b), (c), 0, 0, 0)
#define MFMA32(a, b, c) __builtin_amdgcn_mfma_f32_32x32x16_bf16((a), (b), (c), 0, 0, 0)

__device__ __forceinline__ uint16_t f2b(float f) {
    union { float f; uint32_t u; } v; v.f = f;
    uint32_t u = v.u;
    return (uint16_t)((u + 0x7FFFu + ((u >> 16) & 1u)) >> 16);
}

__device__ __forceinline__ bf16x8 ldb8(const uint16_t* p) {
    return *(const bf16x8*)p;
}

// exp2 as a compiler-visible intrinsic (hazard recognizer must see TRANS op).
__device__ __forceinline__ float exp2_fast(float x) {
#if __has_builtin(__builtin_amdgcn_exp2f)
    return __builtin_amdgcn_exp2f(x);
#else
    return __expf(x * 0.6931471805599453f);
#endif
}

// ---------------------------------------------------------------------------
// Kernel 0: pack weights to bf16.  Wall[320][256] = [Wq;Wk;Wv], ball[320],
// Wobf[256][512].  Wq/bq pre-scaled by log2(e) so attention uses exp2.
// ---------------------------------------------------------------------------
__global__ void pack_kernel(const float* __restrict__ Wq, const float* __restrict__ Wk,
                            const float* __restrict__ Wv, const float* __restrict__ bq,
                            const float* __restrict__ bk, const float* __restrict__ bv,
                            const float* __restrict__ Wo,
                            uint16_t* __restrict__ Wall, uint16_t* __restrict__ Wobf,
                            float* __restrict__ ball) {
    const float LOG2E = 1.4426950408889634f;
    int i = blockIdx.x * blockDim.x + threadIdx.x;
    int stride = gridDim.x * blockDim.x;
    for (int idx = i; idx < 320 * 256; idx += stride) {
        int r = idx >> 8, c = idx & 255;
        float v = (r < 32) ? Wq[r * 256 + c] * LOG2E
                 : (r < 64) ? Wk[(r - 32) * 256 + c]
                            : Wv[(r - 64) * 256 + c];
        Wall[idx] = f2b(v);
    }
    for (int idx = i; idx < 256 * 512; idx += stride) Wobf[idx] = f2b(Wo[idx]);
    for (int idx = i; idx < 320; idx += stride)
        ball[idx] = (idx < 32) ? bq[idx] * LOG2E
                  : (idx < 64) ? bk[idx - 32] : bv[idx - 64];
}

// ---------------------------------------------------------------------------
// Kernel 1: QKV projection.
// grid 256 = b(4) x ntile(64).  Emits:
//   qt[b][n][32]                       (k-contiguous rows)
//   K'[b][ch(128)][ks(2)][n32][c16]    (attn K-frag load = contiguous)
//   V'[b][n/8(512)][c(256)][n%8(8)]    (attn V-frag load = coalesced)
// ---------------------------------------------------------------------------
__global__ __launch_bounds__(256) void qkv_kernel(
    const float* __restrict__ x, const uint16_t* __restrict__ Wall,
    const float* __restrict__ ball, uint16_t* __restrict__ qtg,
    uint16_t* __restrict__ ktg, uint16_t* __restrict__ vg) {
    __shared__ uint16_t xt[64][264];   // [n_local][c], pad 264

    const int b = blockIdx.x >> 6;
    const int n0 = (blockIdx.x & 63) * 64;
    const int t = threadIdx.x;
    const float* xb = x + (size_t)b * 256 * 4096;

    {
        const int nPart = t & 15, cIdx = t >> 4;
#pragma unroll
        for (int rep = 0; rep < 16; rep++) {
            int c = rep * 16 + cIdx;
            float4 f = *(const float4*)(xb + (size_t)c * 4096 + n0 + nPart * 4);
            xt[nPart * 4 + 0][c] = f2b(f.x);
            xt[nPart * 4 + 1][c] = f2b(f.y);
            xt[nPart * 4 + 2][c] = f2b(f.z);
            xt[nPart * 4 + 3][c] = f2b(f.w);
        }
    }
    __syncthreads();

    const int w = t >> 6, lane = t & 63, l15 = lane & 15, g = lane >> 4;

    // --- qk: D[n(64), o(64)], wave w owns m-tile w ---
    f32x4 accqk[4] = {};
#pragma unroll
    for (int ks = 0; ks < 8; ks++) {
        bf16x8 af = ldb8(&xt[w * 16 + l15][ks * 32 + g * 8]);
#pragma unroll
        for (int ot = 0; ot < 4; ot++) {
            bf16x8 bfr = ldb8(Wall + (ot * 16 + l15) * 256 + ks * 32 + g * 8);
            accqk[ot] = MFMA16(af, bfr, accqk[ot]);
        }
    }
#pragma unroll
    for (int ot = 0; ot < 4; ot++) {
        int o = ot * 16 + l15;
        float bias = ball[o];
#pragma unroll
        for (int r = 0; r < 4; r++) {
            int n = n0 + w * 16 + g * 4 + r;
            float v = accqk[ot][r] + bias;
            if (ot < 2) {
                qtg[((size_t)b * 4096 + n) * 32 + o] = f2b(v);
            } else {
                int c = o - 32;
                size_t idx = ((((size_t)b * 128 + (n >> 5)) * 2 + (c >> 4)) * 32
                              + (n & 31)) * 16 + (c & 15);
                ktg[idx] = f2b(v);
            }
        }
    }

    // --- v: D[o(256), n(64)], wave w owns o-tiles 4w..4w+3 ---
    f32x4 accv[4][4] = {};
#pragma unroll
    for (int ks = 0; ks < 8; ks++) {
        bf16x8 av[4], bv4[4];
#pragma unroll
        for (int mt = 0; mt < 4; mt++)
            av[mt] = ldb8(Wall + (64 + (w * 4 + mt) * 16 + l15) * 256 + ks * 32 + g * 8);
#pragma unroll
        for (int nt = 0; nt < 4; nt++)
            bv4[nt] = ldb8(&xt[nt * 16 + l15][ks * 32 + g * 8]);
#pragma unroll
        for (int mt = 0; mt < 4; mt++)
#pragma unroll
            for (int nt = 0; nt < 4; nt++)
                accv[mt][nt] = MFMA16(av[mt], bv4[nt], accv[mt][nt]);
    }
#pragma unroll
    for (int mt = 0; mt < 4; mt++) {
#pragma unroll
        for (int r = 0; r < 4; r++) {
            int o = (w * 4 + mt) * 16 + g * 4 + r;
            float bias = ball[64 + o];
#pragma unroll
            for (int nt = 0; nt < 4; nt++) {
                int n = n0 + nt * 16 + l15;
                size_t idx = (((size_t)b * 512 + (n >> 3)) * 256 + o) * 8 + (n & 7);
                vg[idx] = f2b(accv[mt][nt][r] + bias);
            }
        }
    }
}

// ---------------------------------------------------------------------------
// Kernel 2: flash attention v10 — cooperative S + counted barrier.
// grid 512 = b(4) x mtile(128) (32 m-rows), XCD-swizzled; 4 waves, 2 blk/CU.
// Per chunk: each wave produces one S quarter (MFMA16 + 4 exp), ds_write_b64
// into a pad-36 P tile (conflict-free by bank rotation 18), then
// {lgkmcnt(0); raw s_barrier} — global K/V prefetch loads stay IN FLIGHT
// across the barrier (no vmcnt drain, unlike __syncthreads).  PV reads P
// (ds_read, <=2-way) and does 4 MFMA32 on its 64-channel slice.
// ---------------------------------------------------------------------------
__global__ __launch_bounds__(256, 2) void attn_kernel(
    const uint16_t* __restrict__ qtg, const uint16_t* __restrict__ ktg,
    const uint16_t* __restrict__ vg, uint16_t* __restrict__ og) {
    __shared__ uint16_t pts[2][32][36];   // P double buffer, pad 36 (72B rows)
    __shared__ float lsp[4][16];          // per-wave partial row sums

    const int bid = blockIdx.x;
    const int swz = (bid & 7) * 64 + (bid >> 3);   // XCD-chunked (512%8==0)
    const int b = swz >> 7;
    const int m0 = (swz & 127) * 32;
    const int t = threadIdx.x, w = t >> 6, lane = t & 63;
    const int l15 = lane & 15, g = lane >> 4;
    const int l31 = lane & 31, hi = lane >> 5;
    const int mh = w >> 1, nhf = w & 1;

    const uint16_t* qb = qtg + (size_t)b * 4096 * 32;
    const uint16_t* kb = ktg + (size_t)b * 131072;    // 128*2*32*16
    const uint16_t* vb = vg  + (size_t)b * 1048576;   // 512*256*8

    // S-producer fragments: A = K rows (n), B = Q rows (m), K-dim = c(32)
    const bf16x8 qf = ldb8(qb + (size_t)(m0 + mh * 16 + l15) * 32 + g * 8);
    const uint16_t* kbase = kb + (g >> 1) * 512 + (nhf * 16 + l15) * 16 + (g & 1) * 8;

    // P write address: row m_loc (stride 72B), n-quad wq (8B each)
    const int m_loc = mh * 16 + l15;
    const int wq = nhf * 4 + g;                       // n-quad index 0..7
    char* const pwr = (char*)pts + m_loc * 72 + wq * 8;

    // pa read addresses: row l31, quads (ks*4 + hi*2 + j)
    int prd[2][2];
#pragma unroll
    for (int ks = 0; ks < 2; ks++) {
        prd[ks][0] = l31 * 72 + (ks * 4 + hi * 2) * 8;
        prd[ks][1] = l31 * 72 + (ks * 4 + hi * 2 + 1) * 8;
    }

    // V base: V'[n8][c][8], n8 = ch*4 + ks*2 + hi, c = w*64 + ct*32 + l31
    const uint16_t* vbase = vb + (size_t)hi * 2048 + (w * 64 + l31) * 8;

    f32x16 acc[2] = {};        // [ct]: O[m0..+32][w*64 + ct*32 + l31]
    float lpart = 0.f;

    auto loadK = [&](int ch) -> bf16x8 { return ldb8(kbase + ch * 1024); };
    auto loadV = [&](int ch, bf16x8 (*vf)[2]) {
#pragma unroll
        for (int ct = 0; ct < 2; ct++)
#pragma unroll
            for (int ks = 0; ks < 2; ks++)
                vf[ct][ks] = ldb8(vbase + ch * 8192 + ks * 4096 + ct * 256);
    };

    auto sphase = [&](const bf16x8 kf, char* bufb) {
        f32x4 z = {};
        f32x4 s = MFMA16(kf, qf, z);
        // lane (l15,g) reg r: m = m0+mh*16+l15, n = ch*32 + nhf*16 + g*4 + r
        float e0 = exp2_fast(s[0]), e1 = exp2_fast(s[1]);
        float e2 = exp2_fast(s[2]), e3 = exp2_fast(s[3]);
        lpart += (e0 + e1) + (e2 + e3);
        union { uint2 d; __bf16 h[4]; } u;
        u.h[0] = (__bf16)e0; u.h[1] = (__bf16)e1;
        u.h[2] = (__bf16)e2; u.h[3] = (__bf16)e3;
        *(uint2*)(bufb) = u.d;
    };
    auto pv = [&](const char* bufc, const bf16x8 (*vf)[2]) {
        bf16x8 pa[2];
#pragma unroll
        for (int ks = 0; ks < 2; ks++) {
            union { bf16x8 v; uint2 dd[2]; } up;
            up.dd[0] = *(const uint2*)(bufc + prd[ks][0]);
            up.dd[1] = *(const uint2*)(bufc + prd[ks][1]);
            pa[ks] = up.v;
        }
#pragma unroll
        for (int ks = 0; ks < 2; ks++)
#pragma unroll
            for (int ct = 0; ct < 2; ct++)
                acc[ct] = MFMA32(pa[ks], vf[ct][ks], acc[ct]);
    };

    // Counted barrier: make own LDS writes visible, sync waves, but leave
    // global prefetch loads in flight (no vmcnt drain — unlike __syncthreads).
    auto pbar = [&]() {
        asm volatile("s_waitcnt lgkmcnt(0)" ::: "memory");
        __builtin_amdgcn_s_barrier();
        __builtin_amdgcn_sched_barrier(0);
    };

    char* const buf0 = (char*)pts;
    char* const buf1 = (char*)pts + 2304;   // 32*36*2 B

    bf16x8 kfA = loadK(0), kfB = loadK(1);
    bf16x8 vfA[2][2], vfB[2][2];
    loadV(0, vfA);
    loadV(1, vfB);

    for (int it = 0; it < 128; it += 2) {
        // even chunk -> P buf0
        sphase(kfA, pwr);
        if (it + 2 < 128) kfA = loadK(it + 2);
        pbar();
        pv(buf0, vfA);
        if (it + 2 < 128) loadV(it + 2, vfA);
        // odd chunk -> P buf1
        sphase(kfB, pwr + 2304);
        if (it + 3 < 128) kfB = loadK(it + 3);
        pbar();
        pv(buf1, vfB);
        if (it + 3 < 128) loadV(it + 3, vfB);
    }

    // ---- epilogue: row sums ----
    lpart += __shfl_xor(lpart, 16);
    lpart += __shfl_xor(lpart, 32);
    if (lane < 16) lsp[w][lane] = lpart;        // partial for m=mh*16+lane, n-half nhf
    __syncthreads();

#pragma unroll
    for (int r = 0; r < 16; r++) {
        const int m = (r & 3) + 8 * (r >> 2) + 4 * hi;
        const float l = lsp[2 * (m >> 4)][m & 15] + lsp[2 * (m >> 4) + 1][m & 15];
        const float rinv = 1.0f / l;
        const size_t rowo = ((size_t)b * 4096 + m0 + m) * 256 + w * 64 + l31;
        og[rowo] = f2b(acc[0][r] * rinv);
        og[rowo + 32] = f2b(acc[1][r] * rinv);
    }
}

// ---------------------------------------------------------------------------
// Kernel 3: y = Wo[:, :256] @ out + Wo[:, 256:] @ x + bo.
// ---------------------------------------------------------------------------
__global__ __launch_bounds__(256) void out_kernel(
    const float* __restrict__ x, const uint16_t* __restrict__ og,
    const uint16_t* __restrict__ Wobf, const float* __restrict__ bo,
    float* __restrict__ y) {
    __shared__ uint16_t xt[64][264];

    const int b = blockIdx.x >> 6;
    const int m0 = (blockIdx.x & 63) * 64;
    const int t = threadIdx.x;
    const float* xb = x + (size_t)b * 256 * 4096;

    {
        const int nPart = t & 15, cIdx = t >> 4;
#pragma unroll
        for (int rep = 0; rep < 16; rep++) {
            int c = rep * 16 + cIdx;
            float4 f = *(const float4*)(xb + (size_t)c * 4096 + m0 + nPart * 4);
            xt[nPart * 4 + 0][c] = f2b(f.x);
            xt[nPart * 4 + 1][c] = f2b(f.y);
            xt[nPart * 4 + 2][c] = f2b(f.z);
            xt[nPart * 4 + 3][c] = f2b(f.w);
        }
    }
    __syncthreads();

    const int w = t >> 6, lane = t & 63, l15 = lane & 15, g = lane >> 4;
    const uint16_t* ob = og + ((size_t)b * 4096 + m0) * 256;

    f32x4 acc[4][4] = {};
#pragma unroll
    for (int ks = 0; ks < 8; ks++) {
        bf16x8 af[4], bfr[4];
#pragma unroll
        for (int mt = 0; mt < 4; mt++)
            af[mt] = ldb8(Wobf + ((w * 4 + mt) * 16 + l15) * 512 + ks * 32 + g * 8);
#pragma unroll
        for (int nt = 0; nt < 4; nt++)
            bfr[nt] = ldb8(ob + (size_t)(nt * 16 + l15) * 256 + ks * 32 + g * 8);
#pragma unroll
        for (int mt = 0; mt < 4; mt++)
#pragma unroll
            for (int nt = 0; nt < 4; nt++)
                acc[mt][nt] = MFMA16(af[mt], bfr[nt], acc[mt][nt]);
    }
#pragma unroll
    for (int ks = 0; ks < 8; ks++) {
        bf16x8 af[4], bfr[4];
#pragma unroll
        for (int mt = 0; mt < 4; mt++)
            af[mt] = ldb8(Wobf + ((w * 4 + mt) * 16 + l15) * 512 + 256 + ks * 32 + g * 8);
#pragma unroll
        for (int nt = 0; nt < 4; nt++)
            bfr[nt] = ldb8(&xt[nt * 16 + l15][ks * 32 + g * 8]);
#pragma unroll
        for (int mt = 0; mt < 4; mt++)
#pragma unroll
            for (int nt = 0; nt < 4; nt++)
                acc[mt][nt] = MFMA16(af[mt], bfr[nt], acc[mt][nt]);
    }

#pragma unroll
    for (int mt = 0; mt < 4; mt++)
#pragma unroll
        for (int r = 0; r < 4; r++) {
            int o = (w * 4 + mt) * 16 + g * 4 + r;
            float bias = bo[o];
#pragma unroll
            for (int nt = 0; nt < 4; nt++) {
                int m = m0 + nt * 16 + l15;
                y[((size_t)b * 256 + o) * 4096 + m] = acc[mt][nt][r] + bias;
            }
        }
}

// ---------------------------------------------------------------------------
extern "C" void kernel_launch(void* const* d_in, const int* in_sizes, int n_in,
                              void* d_out, int out_size, void* d_ws, size_t ws_size,
                              hipStream_t stream) {
    const float* x  = (const float*)d_in[0];
    const float* Wq = (const float*)d_in[1];
    const float* bq = (const float*)d_in[2];
    const float* Wk = (const float*)d_in[3];
    const float* bk = (const float*)d_in[4];
    const float* Wv = (const float*)d_in[5];
    const float* bv = (const float*)d_in[6];
    const float* Wo = (const float*)d_in[7];
    const float* bo = (const float*)d_in[8];
    float* y = (float*)d_out;

    char* ws = (char*)d_ws;
    uint16_t* Wall = (uint16_t*)(ws + 0);          // 163840 B
    uint16_t* Wobf = (uint16_t*)(ws + 163840);     // 262144 B
    float*    ball = (float*)(ws + 425984);        // 1280 B
    uint16_t* qtg  = (uint16_t*)(ws + 427520);     // 1 MiB
    uint16_t* ktg  = (uint16_t*)(ws + 1476096);    // 1 MiB
    uint16_t* vgw  = (uint16_t*)(ws + 2524672);    // 8 MiB
    uint16_t* ogw  = (uint16_t*)(ws + 10913280);   // 8 MiB

    pack_kernel<<<256, 256, 0, stream>>>(Wq, Wk, Wv, bq, bk, bv, Wo, Wall, Wobf, ball);
    qkv_kernel<<<256, 256, 0, stream>>>(x, Wall, ball, qtg, ktg, vgw);
    attn_kernel<<<512, 256, 0, stream>>>(qtg, ktg, vgw, ogw);
    out_kernel<<<256, 256, 0, stream>>>(x, ogw, Wobf, bo, y);
}